// Round 3
// baseline (3400.049 us; speedup 1.0000x reference)
//
#include <hip/hip_runtime.h>
#include <cstdint>
#include <cstddef>

// Problem constants (match reference)
#define NNODES 150002      // N_USERS + N_ITEMS + 2
#define DIM    128
#define NEDGE  600000
#define EPSN   1e-12f

// ---------------------------------------------------------------------------
// SpMM: y[rows[e]] += vals[e] * x[cols[e]]  (edge dropped if mask[e]==0)
// 32 lanes per edge, float4 per lane, scalar f32 atomics.
// masks arrive as int32 (harness widens numpy bool to int).
// ---------------------------------------------------------------------------
__global__ void spmm_kernel(const int* __restrict__ rows,
                            const int* __restrict__ cols,
                            const float* __restrict__ vals,
                            const int* __restrict__ mask,
                            const float* __restrict__ x,
                            float* __restrict__ y)
{
    long long gid = (long long)blockIdx.x * blockDim.x + threadIdx.x;
    int e    = (int)(gid >> 5);
    int lane = (int)(gid & 31);
    if (e >= NEDGE) return;
    if (!mask[e]) return;
    float v = vals[e];
    int c = cols[e];
    int r = rows[e];
    float4 xv = *reinterpret_cast<const float4*>(x + (size_t)c * DIM + lane * 4);
    float* dst = y + (size_t)r * DIM + lane * 4;
    atomicAdd(dst + 0, v * xv.x);
    atomicAdd(dst + 1, v * xv.y);
    atomicAdd(dst + 2, v * xv.z);
    atomicAdd(dst + 3, v * xv.w);
}

// Same, but contribution scaled by rowscale[rows[e]] * (1/3)
__global__ void spmm_scaled_kernel(const int* __restrict__ rows,
                                   const int* __restrict__ cols,
                                   const float* __restrict__ vals,
                                   const int* __restrict__ mask,
                                   const float* __restrict__ x,
                                   float* __restrict__ y,
                                   const float* __restrict__ rowscale)
{
    long long gid = (long long)blockIdx.x * blockDim.x + threadIdx.x;
    int e    = (int)(gid >> 5);
    int lane = (int)(gid & 31);
    if (e >= NEDGE) return;
    if (!mask[e]) return;
    int r = rows[e];
    float v = vals[e] * rowscale[r] * (1.0f / 3.0f);
    int c = cols[e];
    float4 xv = *reinterpret_cast<const float4*>(x + (size_t)c * DIM + lane * 4);
    float* dst = y + (size_t)r * DIM + lane * 4;
    atomicAdd(dst + 0, v * xv.x);
    atomicAdd(dst + 1, v * xv.y);
    atomicAdd(dst + 2, v * xv.z);
    atomicAdd(dst + 3, v * xv.w);
}

// ---------------------------------------------------------------------------
// Row-norm epilogue A: out[r] = l2norm(trans[r]*(emb[r]+s[r])/3) + emb[r]
// One 64-lane wave per row, float2 per lane.
// ---------------------------------------------------------------------------
__global__ void rownorm_aux_kernel(const float* __restrict__ emb,
                                   const float* __restrict__ s,
                                   const float* __restrict__ trans,
                                   float* __restrict__ out)
{
    int gid  = blockIdx.x * blockDim.x + threadIdx.x;
    int row  = gid >> 6;
    int lane = gid & 63;
    if (row >= NNODES) return;
    float t = trans[row] * (1.0f / 3.0f);
    size_t base = (size_t)row * DIM + lane * 2;
    float2 e  = *reinterpret_cast<const float2*>(emb + base);
    float2 sv = *reinterpret_cast<const float2*>(s + base);
    float ax = t * (e.x + sv.x);
    float ay = t * (e.y + sv.y);
    float ss = ax * ax + ay * ay;
#pragma unroll
    for (int off = 32; off > 0; off >>= 1) ss += __shfl_xor(ss, off, 64);
    float inv = 1.0f / fmaxf(sqrtf(ss), EPSN);
    float2 o;
    o.x = ax * inv + e.x;
    o.y = ay * inv + e.y;
    *reinterpret_cast<float2*>(out + base) = o;
}

// Final epilogue: agg = b[r] + tbaux[r]/3 * cur_aux[r];
//                 out[r] = l2norm(agg) + cur_aux[r]   (out aliases cur_aux)
__global__ void rownorm_final_kernel(const float* __restrict__ cur_aux,
                                     const float* __restrict__ b,
                                     const float* __restrict__ tbaux,
                                     float* __restrict__ out)
{
    int gid  = blockIdx.x * blockDim.x + threadIdx.x;
    int row  = gid >> 6;
    int lane = gid & 63;
    if (row >= NNODES) return;
    float t = tbaux[row] * (1.0f / 3.0f);
    size_t base = (size_t)row * DIM + lane * 2;
    float2 ca = *reinterpret_cast<const float2*>(cur_aux + base);
    float2 bv = *reinterpret_cast<const float2*>(b + base);
    float ax = bv.x + t * ca.x;
    float ay = bv.y + t * ca.y;
    float ss = ax * ax + ay * ay;
#pragma unroll
    for (int off = 32; off > 0; off >>= 1) ss += __shfl_xor(ss, off, 64);
    float inv = 1.0f / fmaxf(sqrtf(ss), EPSN);
    float2 o;
    o.x = ax * inv + ca.x;
    o.y = ay * inv + ca.y;
    *reinterpret_cast<float2*>(out + base) = o;
}

// ---------------------------------------------------------------------------
// Elementwise: b[i] = tball[row] * (emb[i] + b[i]) / 3       (float4)
// ---------------------------------------------------------------------------
__global__ void combine_all_kernel(const float* __restrict__ emb,
                                   const float* __restrict__ tball,
                                   float* __restrict__ b)
{
    int i = blockIdx.x * blockDim.x + threadIdx.x;
    const int n4 = NNODES * DIM / 4;
    if (i >= n4) return;
    int row = i >> 5;  // (i*4)/128
    float t = tball[row] * (1.0f / 3.0f);
    float4 e  = reinterpret_cast<const float4*>(emb)[i];
    float4 bv = reinterpret_cast<float4*>(b)[i];
    bv.x = t * (e.x + bv.x);
    bv.y = t * (e.y + bv.y);
    bv.z = t * (e.z + bv.z);
    bv.w = t * (e.w + bv.w);
    reinterpret_cast<float4*>(b)[i] = bv;
}

// Elementwise: b[i] += tbaux[row] * a[i] / 3                 (float4)
__global__ void add_scaled_kernel(const float* __restrict__ a,
                                  const float* __restrict__ tbaux,
                                  float* __restrict__ b)
{
    int i = blockIdx.x * blockDim.x + threadIdx.x;
    const int n4 = NNODES * DIM / 4;
    if (i >= n4) return;
    int row = i >> 5;
    float t = tbaux[row] * (1.0f / 3.0f);
    float4 av = reinterpret_cast<const float4*>(a)[i];
    float4 bv = reinterpret_cast<float4*>(b)[i];
    bv.x += t * av.x;
    bv.y += t * av.y;
    bv.z += t * av.z;
    bv.w += t * av.w;
    reinterpret_cast<float4*>(b)[i] = bv;
}

// ---------------------------------------------------------------------------
extern "C" void kernel_launch(void* const* d_in, const int* in_sizes, int n_in,
                              void* d_out, int out_size, void* d_ws, size_t ws_size,
                              hipStream_t stream)
{
    const float* emb        = (const float*)d_in[0];
    const int*   rows_aux   = (const int*)d_in[1];
    const int*   cols_aux   = (const int*)d_in[2];
    const float* vals_aux   = (const float*)d_in[3];
    const int*   rows_buy   = (const int*)d_in[4];
    const int*   cols_buy   = (const int*)d_in[5];
    const float* vals_buy   = (const float*)d_in[6];
    const float* t_aux_all  = (const float*)d_in[7];
    const float* t_buy_all  = (const float*)d_in[8];
    const float* t_buy_aux  = (const float*)d_in[9];
    const int*   masks      = (const int*)d_in[10];   // numpy bool widened to int32

    float* out = (float*)d_out;
    const size_t nd = (size_t)NNODES * DIM;
    const size_t nd_bytes = nd * sizeof(float);
    float* B0 = (float*)d_ws;
    float* B1 = B0 + nd;

    const int SPMM_BLK  = 256;
    const int SPMM_GRID = (int)(((long long)NEDGE * 32 + SPMM_BLK - 1) / SPMM_BLK);
    const int ROW_BLK   = 256;
    const int ROW_GRID  = (NNODES * 64 + ROW_BLK - 1) / ROW_BLK;
    const int EW_BLK    = 256;
    const int EW_GRID   = (int)((nd / 4 + EW_BLK - 1) / EW_BLK);

    // ---- Phase A: behavior 'aux' on aux adjacency, input emb ----
    hipMemsetAsync(B0, 0, nd_bytes, stream);
    spmm_kernel<<<SPMM_GRID, SPMM_BLK, 0, stream>>>(rows_aux, cols_aux, vals_aux,
                                                    masks + 0 * (size_t)NEDGE, emb, B0); // B0 = x1
    hipMemcpyAsync(B1, B0, nd_bytes, hipMemcpyDeviceToDevice, stream);                   // B1 = x1
    spmm_kernel<<<SPMM_GRID, SPMM_BLK, 0, stream>>>(rows_aux, cols_aux, vals_aux,
                                                    masks + 1 * (size_t)NEDGE, B0, B1);  // B1 = x1+x2
    // out (cur_aux) = l2norm(t_aux_all*(emb+B1)/3) + emb
    rownorm_aux_kernel<<<ROW_GRID, ROW_BLK, 0, stream>>>(emb, B1, t_aux_all, out);

    // ---- Phase B: behavior 'buy' ----
    // g_all chain (input emb, buy adjacency)
    hipMemsetAsync(B0, 0, nd_bytes, stream);
    spmm_kernel<<<SPMM_GRID, SPMM_BLK, 0, stream>>>(rows_buy, cols_buy, vals_buy,
                                                    masks + 2 * (size_t)NEDGE, emb, B0); // B0 = b1
    hipMemcpyAsync(B1, B0, nd_bytes, hipMemcpyDeviceToDevice, stream);                   // B1 = b1
    spmm_kernel<<<SPMM_GRID, SPMM_BLK, 0, stream>>>(rows_buy, cols_buy, vals_buy,
                                                    masks + 3 * (size_t)NEDGE, B0, B1);  // B1 = b1+b2
    // B1 = t_buy_all * (emb + b1 + b2) / 3      (== t_buy_all * g_all)
    combine_all_kernel<<<EW_GRID, EW_BLK, 0, stream>>>(emb, t_buy_all, B1);

    // g_aux chain (input cur_aux = out, buy adjacency)
    hipMemsetAsync(B0, 0, nd_bytes, stream);
    spmm_kernel<<<SPMM_GRID, SPMM_BLK, 0, stream>>>(rows_buy, cols_buy, vals_buy,
                                                    masks + 4 * (size_t)NEDGE, out, B0); // B0 = a1
    // B1 += t_buy_aux * a1 / 3
    add_scaled_kernel<<<EW_GRID, EW_BLK, 0, stream>>>(B0, t_buy_aux, B1);
    // B1 += t_buy_aux * a2 / 3   (a2 = spmm(m5, a1)), scale folded into atomics
    spmm_scaled_kernel<<<SPMM_GRID, SPMM_BLK, 0, stream>>>(rows_buy, cols_buy, vals_buy,
                                                           masks + 5 * (size_t)NEDGE, B0, B1,
                                                           t_buy_aux);
    // out = l2norm(B1 + t_buy_aux*cur_aux/3) + cur_aux   (cur_aux aliases out, row-local)
    rownorm_final_kernel<<<ROW_GRID, ROW_BLK, 0, stream>>>(out, B1, t_buy_aux, out);
}

// Round 4
// 1423.218 us; speedup vs baseline: 2.3890x; 2.3890x over previous
//
#include <hip/hip_runtime.h>
#include <cstdint>
#include <cstddef>

// Problem constants (match reference)
#define NNODES 150002      // N_USERS + N_ITEMS + 2
#define DIM    128
#define NEDGE  600000
#define EPSN   1e-12f

// ===========================================================================
// CSR-GATHER PATH (primary): build CSR per adjacency on device, then
// atomic-free gather SpMMs with fused row-local epilogues.
// Entry packing: 8 B/edge = { col | mask_bits<<24 , val }.
// ===========================================================================

__global__ void hist_kernel(const int* __restrict__ rows, int* __restrict__ cnt)
{
    int e = blockIdx.x * blockDim.x + threadIdx.x;
    if (e >= NEDGE) return;
    atomicAdd(&cnt[rows[e]], 1);
}

// Single-workgroup exclusive scan of cnt[NNODES] -> row_ptr[NNODES+1], cursor copy.
__global__ __launch_bounds__(1024)
void scan_kernel(const int* __restrict__ cnt,
                 int* __restrict__ row_ptr,
                 int* __restrict__ cursor)
{
    __shared__ int lds[1024];
    const int T  = 1024;
    const int CH = (NNODES + T - 1) / T;   // 147
    int t = threadIdx.x;
    int base = t * CH;
    int s = 0;
    for (int i = 0; i < CH; ++i) {
        int idx = base + i;
        if (idx < NNODES) s += cnt[idx];
    }
    lds[t] = s;
    __syncthreads();
    // inclusive Hillis-Steele scan over 1024 partials
    for (int off = 1; off < T; off <<= 1) {
        int v = (t >= off) ? lds[t - off] : 0;
        __syncthreads();
        lds[t] += v;
        __syncthreads();
    }
    int run = (t == 0) ? 0 : lds[t - 1];
    for (int i = 0; i < CH; ++i) {
        int idx = base + i;
        if (idx < NNODES) {
            row_ptr[idx] = run;
            cursor[idx]  = run;
            run += cnt[idx];
        }
    }
    if (t == T - 1) row_ptr[NNODES] = run;
}

__global__ void scatter_kernel(const int* __restrict__ rows,
                               const int* __restrict__ cols,
                               const float* __restrict__ vals,
                               const int* __restrict__ masks_base, int nmasks,
                               int* __restrict__ cursor,
                               uint2* __restrict__ entries)
{
    int e = blockIdx.x * blockDim.x + threadIdx.x;
    if (e >= NEDGE) return;
    unsigned bits = 0;
    for (int k = 0; k < nmasks; ++k)
        bits |= (masks_base[(size_t)k * NEDGE + e] != 0 ? 1u : 0u) << k;
    int r = rows[e];
    int pos = atomicAdd(&cursor[r], 1);
    entries[pos] = make_uint2((unsigned)cols[e] | (bits << 24), __float_as_uint(vals[e]));
}

// Per-row gather: acc(lane) = sum over edges with mask bit set of val * x[col][lane*2..]
__device__ __forceinline__ float2 row_gather(const int* __restrict__ rp,
                                             const uint2* __restrict__ ent,
                                             int row, int lane, int bit,
                                             const float* __restrict__ x)
{
    int start = rp[row];
    int end   = rp[row + 1];
    float2 acc = make_float2(0.f, 0.f);
    for (int j = start; j < end; ++j) {
        uint2 E = ent[j];
        if ((E.x >> (24 + bit)) & 1u) {
            unsigned col = E.x & 0xFFFFFFu;
            float v = __uint_as_float(E.y);
            const float2 xv = *reinterpret_cast<const float2*>(
                x + (size_t)col * DIM + lane * 2);
            acc.x += v * xv.x;
            acc.y += v * xv.y;
        }
    }
    return acc;
}

#define ROW_SETUP                                                     \
    int row  = blockIdx.x * 4 + (threadIdx.x >> 6);                   \
    int lane = threadIdx.x & 63;                                      \
    if (row >= NNODES) return;                                        \
    row = __builtin_amdgcn_readfirstlane(row);                        \
    size_t base = (size_t)row * DIM + lane * 2;

// y[row] = gather  (covers memset: rows with no active edges write 0)
__global__ void gather_plain_kernel(const int* __restrict__ rp,
                                    const uint2* __restrict__ ent, int bit,
                                    const float* __restrict__ x,
                                    float* __restrict__ y)
{
    ROW_SETUP
    float2 acc = row_gather(rp, ent, row, lane, bit, x);
    *reinterpret_cast<float2*>(y + base) = acc;
}

// out = l2norm( t/3 * (emb + xb + gather) ) + emb      (aux epilogue)
__global__ void gather_fused_aux_kernel(const int* __restrict__ rp,
                                        const uint2* __restrict__ ent, int bit,
                                        const float* __restrict__ xb,   // x1
                                        const float* __restrict__ emb,
                                        const float* __restrict__ trans,
                                        float* __restrict__ out)
{
    ROW_SETUP
    float2 acc = row_gather(rp, ent, row, lane, bit, xb);
    float t = trans[row] * (1.0f / 3.0f);
    float2 e = *reinterpret_cast<const float2*>(emb + base);
    float2 b = *reinterpret_cast<const float2*>(xb + base);
    float ax = t * (e.x + b.x + acc.x);
    float ay = t * (e.y + b.y + acc.y);
    float ss = ax * ax + ay * ay;
#pragma unroll
    for (int off = 32; off > 0; off >>= 1) ss += __shfl_xor(ss, off, 64);
    float inv = 1.0f / fmaxf(sqrtf(ss), EPSN);
    float2 o;
    o.x = ax * inv + e.x;
    o.y = ay * inv + e.y;
    *reinterpret_cast<float2*>(out + base) = o;
}

// yB1 = t/3 * (emb + xb + gather)                      (t_buy_all * g_all)
__global__ void gather_fused_lin_kernel(const int* __restrict__ rp,
                                        const uint2* __restrict__ ent, int bit,
                                        const float* __restrict__ xb,   // b1
                                        const float* __restrict__ emb,
                                        const float* __restrict__ trans,
                                        float* __restrict__ yB1)
{
    ROW_SETUP
    float2 acc = row_gather(rp, ent, row, lane, bit, xb);
    float t = trans[row] * (1.0f / 3.0f);
    float2 e = *reinterpret_cast<const float2*>(emb + base);
    float2 b = *reinterpret_cast<const float2*>(xb + base);
    float2 o;
    o.x = t * (e.x + b.x + acc.x);
    o.y = t * (e.y + b.y + acc.y);
    *reinterpret_cast<float2*>(yB1 + base) = o;
}

// agg = B1 + t/3*(cur + xb + gather); out = l2norm(agg) + cur   (in-place over cur)
__global__ void gather_fused_final_kernel(const int* __restrict__ rp,
                                          const uint2* __restrict__ ent, int bit,
                                          const float* __restrict__ xb,   // a1
                                          const float* __restrict__ B1,
                                          const float* __restrict__ trans,
                                          float* __restrict__ cur_out)    // cur_aux in, cur_buy out
{
    ROW_SETUP
    float2 acc = row_gather(rp, ent, row, lane, bit, xb);
    float t = trans[row] * (1.0f / 3.0f);
    float2 c  = *reinterpret_cast<const float2*>(cur_out + base);
    float2 b  = *reinterpret_cast<const float2*>(xb + base);
    float2 b1 = *reinterpret_cast<const float2*>(B1 + base);
    float ax = b1.x + t * (c.x + b.x + acc.x);
    float ay = b1.y + t * (c.y + b.y + acc.y);
    float ss = ax * ax + ay * ay;
#pragma unroll
    for (int off = 32; off > 0; off >>= 1) ss += __shfl_xor(ss, off, 64);
    float inv = 1.0f / fmaxf(sqrtf(ss), EPSN);
    float2 o;
    o.x = ax * inv + c.x;
    o.y = ay * inv + c.y;
    *reinterpret_cast<float2*>(cur_out + base) = o;
}

// ===========================================================================
// FALLBACK PATH (Round-3 proven atomic scatter) — used only if ws too small.
// ===========================================================================
__global__ void spmm_kernel(const int* __restrict__ rows, const int* __restrict__ cols,
                            const float* __restrict__ vals, const int* __restrict__ mask,
                            const float* __restrict__ x, float* __restrict__ y)
{
    long long gid = (long long)blockIdx.x * blockDim.x + threadIdx.x;
    int e = (int)(gid >> 5); int lane = (int)(gid & 31);
    if (e >= NEDGE) return;
    if (!mask[e]) return;
    float v = vals[e]; int c = cols[e]; int r = rows[e];
    float4 xv = *reinterpret_cast<const float4*>(x + (size_t)c * DIM + lane * 4);
    float* dst = y + (size_t)r * DIM + lane * 4;
    atomicAdd(dst + 0, v * xv.x); atomicAdd(dst + 1, v * xv.y);
    atomicAdd(dst + 2, v * xv.z); atomicAdd(dst + 3, v * xv.w);
}

__global__ void spmm_scaled_kernel(const int* __restrict__ rows, const int* __restrict__ cols,
                                   const float* __restrict__ vals, const int* __restrict__ mask,
                                   const float* __restrict__ x, float* __restrict__ y,
                                   const float* __restrict__ rowscale)
{
    long long gid = (long long)blockIdx.x * blockDim.x + threadIdx.x;
    int e = (int)(gid >> 5); int lane = (int)(gid & 31);
    if (e >= NEDGE) return;
    if (!mask[e]) return;
    int r = rows[e];
    float v = vals[e] * rowscale[r] * (1.0f / 3.0f);
    int c = cols[e];
    float4 xv = *reinterpret_cast<const float4*>(x + (size_t)c * DIM + lane * 4);
    float* dst = y + (size_t)r * DIM + lane * 4;
    atomicAdd(dst + 0, v * xv.x); atomicAdd(dst + 1, v * xv.y);
    atomicAdd(dst + 2, v * xv.z); atomicAdd(dst + 3, v * xv.w);
}

__global__ void rownorm_aux_kernel(const float* __restrict__ emb, const float* __restrict__ s,
                                   const float* __restrict__ trans, float* __restrict__ out)
{
    int gid = blockIdx.x * blockDim.x + threadIdx.x;
    int row = gid >> 6; int lane = gid & 63;
    if (row >= NNODES) return;
    float t = trans[row] * (1.0f / 3.0f);
    size_t base = (size_t)row * DIM + lane * 2;
    float2 e  = *reinterpret_cast<const float2*>(emb + base);
    float2 sv = *reinterpret_cast<const float2*>(s + base);
    float ax = t * (e.x + sv.x); float ay = t * (e.y + sv.y);
    float ss = ax * ax + ay * ay;
#pragma unroll
    for (int off = 32; off > 0; off >>= 1) ss += __shfl_xor(ss, off, 64);
    float inv = 1.0f / fmaxf(sqrtf(ss), EPSN);
    float2 o; o.x = ax * inv + e.x; o.y = ay * inv + e.y;
    *reinterpret_cast<float2*>(out + base) = o;
}

__global__ void rownorm_final_kernel(const float* __restrict__ cur_aux, const float* __restrict__ b,
                                     const float* __restrict__ tbaux, float* __restrict__ out)
{
    int gid = blockIdx.x * blockDim.x + threadIdx.x;
    int row = gid >> 6; int lane = gid & 63;
    if (row >= NNODES) return;
    float t = tbaux[row] * (1.0f / 3.0f);
    size_t base = (size_t)row * DIM + lane * 2;
    float2 ca = *reinterpret_cast<const float2*>(cur_aux + base);
    float2 bv = *reinterpret_cast<const float2*>(b + base);
    float ax = bv.x + t * ca.x; float ay = bv.y + t * ca.y;
    float ss = ax * ax + ay * ay;
#pragma unroll
    for (int off = 32; off > 0; off >>= 1) ss += __shfl_xor(ss, off, 64);
    float inv = 1.0f / fmaxf(sqrtf(ss), EPSN);
    float2 o; o.x = ax * inv + ca.x; o.y = ay * inv + ca.y;
    *reinterpret_cast<float2*>(out + base) = o;
}

__global__ void combine_all_kernel(const float* __restrict__ emb, const float* __restrict__ tball,
                                   float* __restrict__ b)
{
    int i = blockIdx.x * blockDim.x + threadIdx.x;
    const int n4 = NNODES * DIM / 4;
    if (i >= n4) return;
    int row = i >> 5;
    float t = tball[row] * (1.0f / 3.0f);
    float4 e  = reinterpret_cast<const float4*>(emb)[i];
    float4 bv = reinterpret_cast<float4*>(b)[i];
    bv.x = t * (e.x + bv.x); bv.y = t * (e.y + bv.y);
    bv.z = t * (e.z + bv.z); bv.w = t * (e.w + bv.w);
    reinterpret_cast<float4*>(b)[i] = bv;
}

__global__ void add_scaled_kernel(const float* __restrict__ a, const float* __restrict__ tbaux,
                                  float* __restrict__ b)
{
    int i = blockIdx.x * blockDim.x + threadIdx.x;
    const int n4 = NNODES * DIM / 4;
    if (i >= n4) return;
    int row = i >> 5;
    float t = tbaux[row] * (1.0f / 3.0f);
    float4 av = reinterpret_cast<const float4*>(a)[i];
    float4 bv = reinterpret_cast<float4*>(b)[i];
    bv.x += t * av.x; bv.y += t * av.y; bv.z += t * av.z; bv.w += t * av.w;
    reinterpret_cast<float4*>(b)[i] = bv;
}

// ===========================================================================
extern "C" void kernel_launch(void* const* d_in, const int* in_sizes, int n_in,
                              void* d_out, int out_size, void* d_ws, size_t ws_size,
                              hipStream_t stream)
{
    const float* emb       = (const float*)d_in[0];
    const int*   rows_aux  = (const int*)d_in[1];
    const int*   cols_aux  = (const int*)d_in[2];
    const float* vals_aux  = (const float*)d_in[3];
    const int*   rows_buy  = (const int*)d_in[4];
    const int*   cols_buy  = (const int*)d_in[5];
    const float* vals_buy  = (const float*)d_in[6];
    const float* t_aux_all = (const float*)d_in[7];
    const float* t_buy_all = (const float*)d_in[8];
    const float* t_buy_aux = (const float*)d_in[9];
    const int*   masks     = (const int*)d_in[10];   // numpy bool widened to int32

    float* out = (float*)d_out;
    const size_t nd = (size_t)NNODES * DIM;
    const size_t nd_bytes = nd * sizeof(float);

    // ---- workspace layout (16B-aligned regions) ----
    uint8_t* wsb = (uint8_t*)d_ws;
    size_t off = 0;
    auto carve = [&](size_t bytes) -> void* {
        void* p = wsb + off;
        off = (off + bytes + 15) & ~(size_t)15;
        return p;
    };
    float* B0       = (float*)carve(nd_bytes);
    float* B1       = (float*)carve(nd_bytes);
    uint2* ent_aux  = (uint2*)carve((size_t)NEDGE * 8);
    uint2* ent_buy  = (uint2*)carve((size_t)NEDGE * 8);
    int*   rp_aux   = (int*)carve((NNODES + 1) * 4);
    int*   rp_buy   = (int*)carve((NNODES + 1) * 4);
    int*   cursor   = (int*)carve((NNODES + 1) * 4);
    int*   cnt      = (int*)carve((size_t)NNODES * 4);
    const bool use_csr = (off <= ws_size);

    const int EDGE_BLK  = 256;
    const int EDGE_GRID = (NEDGE + EDGE_BLK - 1) / EDGE_BLK;
    const int GROW_BLK  = 256;                      // 4 waves = 4 rows per block
    const int GROW_GRID = (NNODES + 3) / 4;

    if (use_csr) {
        // ---- CSR build: aux (mask bits 0..1), buy (mask bits 0..3 = global 2..5) ----
        hipMemsetAsync(cnt, 0, (size_t)NNODES * 4, stream);
        hist_kernel<<<EDGE_GRID, EDGE_BLK, 0, stream>>>(rows_aux, cnt);
        scan_kernel<<<1, 1024, 0, stream>>>(cnt, rp_aux, cursor);
        scatter_kernel<<<EDGE_GRID, EDGE_BLK, 0, stream>>>(rows_aux, cols_aux, vals_aux,
                                                           masks + 0 * (size_t)NEDGE, 2,
                                                           cursor, ent_aux);
        hipMemsetAsync(cnt, 0, (size_t)NNODES * 4, stream);
        hist_kernel<<<EDGE_GRID, EDGE_BLK, 0, stream>>>(rows_buy, cnt);
        scan_kernel<<<1, 1024, 0, stream>>>(cnt, rp_buy, cursor);
        scatter_kernel<<<EDGE_GRID, EDGE_BLK, 0, stream>>>(rows_buy, cols_buy, vals_buy,
                                                           masks + 2 * (size_t)NEDGE, 4,
                                                           cursor, ent_buy);

        // ---- Phase A: aux behavior ----
        gather_plain_kernel<<<GROW_GRID, GROW_BLK, 0, stream>>>(rp_aux, ent_aux, 0, emb, B0); // x1
        gather_fused_aux_kernel<<<GROW_GRID, GROW_BLK, 0, stream>>>(rp_aux, ent_aux, 1,
                                                                    B0, emb, t_aux_all, out); // cur_aux

        // ---- Phase B: buy behavior ----
        gather_plain_kernel<<<GROW_GRID, GROW_BLK, 0, stream>>>(rp_buy, ent_buy, 0, emb, B0); // b1
        gather_fused_lin_kernel<<<GROW_GRID, GROW_BLK, 0, stream>>>(rp_buy, ent_buy, 1,
                                                                    B0, emb, t_buy_all, B1);  // t*g_all
        gather_plain_kernel<<<GROW_GRID, GROW_BLK, 0, stream>>>(rp_buy, ent_buy, 2, out, B0); // a1
        gather_fused_final_kernel<<<GROW_GRID, GROW_BLK, 0, stream>>>(rp_buy, ent_buy, 3,
                                                                      B0, B1, t_buy_aux, out);
        return;
    }

    // ---- fallback: Round-3 atomic path ----
    const int SPMM_BLK  = 256;
    const int SPMM_GRID = (int)(((long long)NEDGE * 32 + SPMM_BLK - 1) / SPMM_BLK);
    const int ROW_BLK   = 256;
    const int ROW_GRID  = (NNODES * 64 + ROW_BLK - 1) / ROW_BLK;
    const int EW_BLK    = 256;
    const int EW_GRID   = (int)((nd / 4 + EW_BLK - 1) / EW_BLK);

    hipMemsetAsync(B0, 0, nd_bytes, stream);
    spmm_kernel<<<SPMM_GRID, SPMM_BLK, 0, stream>>>(rows_aux, cols_aux, vals_aux,
                                                    masks + 0 * (size_t)NEDGE, emb, B0);
    hipMemcpyAsync(B1, B0, nd_bytes, hipMemcpyDeviceToDevice, stream);
    spmm_kernel<<<SPMM_GRID, SPMM_BLK, 0, stream>>>(rows_aux, cols_aux, vals_aux,
                                                    masks + 1 * (size_t)NEDGE, B0, B1);
    rownorm_aux_kernel<<<ROW_GRID, ROW_BLK, 0, stream>>>(emb, B1, t_aux_all, out);

    hipMemsetAsync(B0, 0, nd_bytes, stream);
    spmm_kernel<<<SPMM_GRID, SPMM_BLK, 0, stream>>>(rows_buy, cols_buy, vals_buy,
                                                    masks + 2 * (size_t)NEDGE, emb, B0);
    hipMemcpyAsync(B1, B0, nd_bytes, hipMemcpyDeviceToDevice, stream);
    spmm_kernel<<<SPMM_GRID, SPMM_BLK, 0, stream>>>(rows_buy, cols_buy, vals_buy,
                                                    masks + 3 * (size_t)NEDGE, B0, B1);
    combine_all_kernel<<<EW_GRID, EW_BLK, 0, stream>>>(emb, t_buy_all, B1);

    hipMemsetAsync(B0, 0, nd_bytes, stream);
    spmm_kernel<<<SPMM_GRID, SPMM_BLK, 0, stream>>>(rows_buy, cols_buy, vals_buy,
                                                    masks + 4 * (size_t)NEDGE, out, B0);
    add_scaled_kernel<<<EW_GRID, EW_BLK, 0, stream>>>(B0, t_buy_aux, B1);
    spmm_scaled_kernel<<<SPMM_GRID, SPMM_BLK, 0, stream>>>(rows_buy, cols_buy, vals_buy,
                                                           masks + 5 * (size_t)NEDGE, B0, B1,
                                                           t_buy_aux);
    rownorm_final_kernel<<<ROW_GRID, ROW_BLK, 0, stream>>>(out, B1, t_buy_aux, out);
}

// Round 5
// 654.894 us; speedup vs baseline: 5.1918x; 2.1732x over previous
//
#include <hip/hip_runtime.h>
#include <cstdint>
#include <cstddef>

// Problem constants (match reference)
#define NNODES 150002      // N_USERS + N_ITEMS + 2
#define DIM    128
#define NEDGE  600000
#define EPSN   1e-12f

// ===========================================================================
// CSR-GATHER PATH: build CSR per adjacency on device (3-phase parallel scan),
// then atomic-free gather SpMMs with fused row-local epilogues.
// Entry packing: 8 B/edge = { col | mask_bits<<24 , val }.
// ===========================================================================

__global__ void hist_kernel(const int* __restrict__ rows, int* __restrict__ cnt)
{
    int e = blockIdx.x * blockDim.x + threadIdx.x;
    if (e >= NEDGE) return;
    atomicAdd(&cnt[rows[e]], 1);
}

// Phase 1: per-block (1024-wide) exclusive scan of cnt -> row_ptr (local), block sums -> partials
__global__ __launch_bounds__(1024)
void scan_phase1(const int* __restrict__ cnt,
                 int* __restrict__ local,      // row_ptr used as temp (block-local exclusive)
                 int* __restrict__ partials)
{
    __shared__ int lds[1024];
    int t = threadIdx.x;
    int i = blockIdx.x * 1024 + t;
    int v = (i < NNODES) ? cnt[i] : 0;
    lds[t] = v;
    __syncthreads();
    for (int off = 1; off < 1024; off <<= 1) {
        int w = (t >= off) ? lds[t - off] : 0;
        __syncthreads();
        lds[t] += w;
        __syncthreads();
    }
    if (i < NNODES) local[i] = lds[t] - v;     // exclusive within block
    if (t == 1023) partials[blockIdx.x] = lds[1023];
}

// Phase 2: single block exclusive-scans the block partials in place (nparts <= 256)
__global__ void scan_phase2(int* __restrict__ partials, int nparts)
{
    __shared__ int lds[256];
    int t = threadIdx.x;
    int v = (t < nparts) ? partials[t] : 0;
    lds[t] = v;
    __syncthreads();
    for (int off = 1; off < 256; off <<= 1) {
        int w = (t >= off) ? lds[t - off] : 0;
        __syncthreads();
        lds[t] += w;
        __syncthreads();
    }
    if (t < nparts) partials[t] = lds[t] - v;  // exclusive
}

// Phase 3: add scanned block offsets; produce final row_ptr and cursor copy.
// Total over all rows is always NEDGE (hist counts every edge).
__global__ __launch_bounds__(1024)
void scan_phase3(int* __restrict__ row_ptr,
                 const int* __restrict__ partials,
                 int* __restrict__ cursor)
{
    int i = blockIdx.x * 1024 + threadIdx.x;
    if (i >= NNODES) return;
    int v = row_ptr[i] + partials[blockIdx.x];
    row_ptr[i] = v;
    cursor[i]  = v;
    if (i == 0) row_ptr[NNODES] = NEDGE;
}

__global__ void scatter_kernel(const int* __restrict__ rows,
                               const int* __restrict__ cols,
                               const float* __restrict__ vals,
                               const int* __restrict__ masks_base, int nmasks,
                               int* __restrict__ cursor,
                               uint2* __restrict__ entries)
{
    int e = blockIdx.x * blockDim.x + threadIdx.x;
    if (e >= NEDGE) return;
    unsigned bits = 0;
    for (int k = 0; k < nmasks; ++k)
        bits |= (masks_base[(size_t)k * NEDGE + e] != 0 ? 1u : 0u) << k;
    int r = rows[e];
    int pos = atomicAdd(&cursor[r], 1);
    entries[pos] = make_uint2((unsigned)cols[e] | (bits << 24), __float_as_uint(vals[e]));
}

// Per-row gather: acc(lane) = sum over edges with mask bit set of val * x[col][lane*2..]
__device__ __forceinline__ float2 row_gather(const int* __restrict__ rp,
                                             const uint2* __restrict__ ent,
                                             int row, int lane, int bit,
                                             const float* __restrict__ x)
{
    int start = rp[row];
    int end   = rp[row + 1];
    float2 acc = make_float2(0.f, 0.f);
    for (int j = start; j < end; ++j) {
        uint2 E = ent[j];
        if ((E.x >> (24 + bit)) & 1u) {
            unsigned col = E.x & 0xFFFFFFu;
            float v = __uint_as_float(E.y);
            const float2 xv = *reinterpret_cast<const float2*>(
                x + (size_t)col * DIM + lane * 2);
            acc.x += v * xv.x;
            acc.y += v * xv.y;
        }
    }
    return acc;
}

#define ROW_SETUP                                                     \
    int row  = blockIdx.x * 4 + (threadIdx.x >> 6);                   \
    int lane = threadIdx.x & 63;                                      \
    if (row >= NNODES) return;                                        \
    row = __builtin_amdgcn_readfirstlane(row);                        \
    size_t base = (size_t)row * DIM + lane * 2;

// y[row] = gather  (covers memset: rows with no active edges write 0)
__global__ void gather_plain_kernel(const int* __restrict__ rp,
                                    const uint2* __restrict__ ent, int bit,
                                    const float* __restrict__ x,
                                    float* __restrict__ y)
{
    ROW_SETUP
    float2 acc = row_gather(rp, ent, row, lane, bit, x);
    *reinterpret_cast<float2*>(y + base) = acc;
}

// out = l2norm( t/3 * (emb + xb + gather) ) + emb      (aux epilogue)
__global__ void gather_fused_aux_kernel(const int* __restrict__ rp,
                                        const uint2* __restrict__ ent, int bit,
                                        const float* __restrict__ xb,   // x1
                                        const float* __restrict__ emb,
                                        const float* __restrict__ trans,
                                        float* __restrict__ out)
{
    ROW_SETUP
    float2 acc = row_gather(rp, ent, row, lane, bit, xb);
    float t = trans[row] * (1.0f / 3.0f);
    float2 e = *reinterpret_cast<const float2*>(emb + base);
    float2 b = *reinterpret_cast<const float2*>(xb + base);
    float ax = t * (e.x + b.x + acc.x);
    float ay = t * (e.y + b.y + acc.y);
    float ss = ax * ax + ay * ay;
#pragma unroll
    for (int off = 32; off > 0; off >>= 1) ss += __shfl_xor(ss, off, 64);
    float inv = 1.0f / fmaxf(sqrtf(ss), EPSN);
    float2 o;
    o.x = ax * inv + e.x;
    o.y = ay * inv + e.y;
    *reinterpret_cast<float2*>(out + base) = o;
}

// yB1 = t/3 * (emb + xb + gather)                      (t_buy_all * g_all)
__global__ void gather_fused_lin_kernel(const int* __restrict__ rp,
                                        const uint2* __restrict__ ent, int bit,
                                        const float* __restrict__ xb,   // b1
                                        const float* __restrict__ emb,
                                        const float* __restrict__ trans,
                                        float* __restrict__ yB1)
{
    ROW_SETUP
    float2 acc = row_gather(rp, ent, row, lane, bit, xb);
    float t = trans[row] * (1.0f / 3.0f);
    float2 e = *reinterpret_cast<const float2*>(emb + base);
    float2 b = *reinterpret_cast<const float2*>(xb + base);
    float2 o;
    o.x = t * (e.x + b.x + acc.x);
    o.y = t * (e.y + b.y + acc.y);
    *reinterpret_cast<float2*>(yB1 + base) = o;
}

// agg = B1 + t/3*(cur + xb + gather); out = l2norm(agg) + cur   (in-place over cur)
__global__ void gather_fused_final_kernel(const int* __restrict__ rp,
                                          const uint2* __restrict__ ent, int bit,
                                          const float* __restrict__ xb,   // a1
                                          const float* __restrict__ B1,
                                          const float* __restrict__ trans,
                                          float* __restrict__ cur_out)    // cur_aux in, cur_buy out
{
    ROW_SETUP
    float2 acc = row_gather(rp, ent, row, lane, bit, xb);
    float t = trans[row] * (1.0f / 3.0f);
    float2 c  = *reinterpret_cast<const float2*>(cur_out + base);
    float2 b  = *reinterpret_cast<const float2*>(xb + base);
    float2 b1 = *reinterpret_cast<const float2*>(B1 + base);
    float ax = b1.x + t * (c.x + b.x + acc.x);
    float ay = b1.y + t * (c.y + b.y + acc.y);
    float ss = ax * ax + ay * ay;
#pragma unroll
    for (int off = 32; off > 0; off >>= 1) ss += __shfl_xor(ss, off, 64);
    float inv = 1.0f / fmaxf(sqrtf(ss), EPSN);
    float2 o;
    o.x = ax * inv + c.x;
    o.y = ay * inv + c.y;
    *reinterpret_cast<float2*>(cur_out + base) = o;
}

// ===========================================================================
// FALLBACK PATH (Round-3 proven atomic scatter) — used only if ws too small.
// ===========================================================================
__global__ void spmm_kernel(const int* __restrict__ rows, const int* __restrict__ cols,
                            const float* __restrict__ vals, const int* __restrict__ mask,
                            const float* __restrict__ x, float* __restrict__ y)
{
    long long gid = (long long)blockIdx.x * blockDim.x + threadIdx.x;
    int e = (int)(gid >> 5); int lane = (int)(gid & 31);
    if (e >= NEDGE) return;
    if (!mask[e]) return;
    float v = vals[e]; int c = cols[e]; int r = rows[e];
    float4 xv = *reinterpret_cast<const float4*>(x + (size_t)c * DIM + lane * 4);
    float* dst = y + (size_t)r * DIM + lane * 4;
    atomicAdd(dst + 0, v * xv.x); atomicAdd(dst + 1, v * xv.y);
    atomicAdd(dst + 2, v * xv.z); atomicAdd(dst + 3, v * xv.w);
}

__global__ void spmm_scaled_kernel(const int* __restrict__ rows, const int* __restrict__ cols,
                                   const float* __restrict__ vals, const int* __restrict__ mask,
                                   const float* __restrict__ x, float* __restrict__ y,
                                   const float* __restrict__ rowscale)
{
    long long gid = (long long)blockIdx.x * blockDim.x + threadIdx.x;
    int e = (int)(gid >> 5); int lane = (int)(gid & 31);
    if (e >= NEDGE) return;
    if (!mask[e]) return;
    int r = rows[e];
    float v = vals[e] * rowscale[r] * (1.0f / 3.0f);
    int c = cols[e];
    float4 xv = *reinterpret_cast<const float4*>(x + (size_t)c * DIM + lane * 4);
    float* dst = y + (size_t)r * DIM + lane * 4;
    atomicAdd(dst + 0, v * xv.x); atomicAdd(dst + 1, v * xv.y);
    atomicAdd(dst + 2, v * xv.z); atomicAdd(dst + 3, v * xv.w);
}

__global__ void rownorm_aux_kernel(const float* __restrict__ emb, const float* __restrict__ s,
                                   const float* __restrict__ trans, float* __restrict__ out)
{
    int gid = blockIdx.x * blockDim.x + threadIdx.x;
    int row = gid >> 6; int lane = gid & 63;
    if (row >= NNODES) return;
    float t = trans[row] * (1.0f / 3.0f);
    size_t base = (size_t)row * DIM + lane * 2;
    float2 e  = *reinterpret_cast<const float2*>(emb + base);
    float2 sv = *reinterpret_cast<const float2*>(s + base);
    float ax = t * (e.x + sv.x); float ay = t * (e.y + sv.y);
    float ss = ax * ax + ay * ay;
#pragma unroll
    for (int off = 32; off > 0; off >>= 1) ss += __shfl_xor(ss, off, 64);
    float inv = 1.0f / fmaxf(sqrtf(ss), EPSN);
    float2 o; o.x = ax * inv + e.x; o.y = ay * inv + e.y;
    *reinterpret_cast<float2*>(out + base) = o;
}

__global__ void rownorm_final_kernel(const float* __restrict__ cur_aux, const float* __restrict__ b,
                                     const float* __restrict__ tbaux, float* __restrict__ out)
{
    int gid = blockIdx.x * blockDim.x + threadIdx.x;
    int row = gid >> 6; int lane = gid & 63;
    if (row >= NNODES) return;
    float t = tbaux[row] * (1.0f / 3.0f);
    size_t base = (size_t)row * DIM + lane * 2;
    float2 ca = *reinterpret_cast<const float2*>(cur_aux + base);
    float2 bv = *reinterpret_cast<const float2*>(b + base);
    float ax = bv.x + t * ca.x; float ay = bv.y + t * ca.y;
    float ss = ax * ax + ay * ay;
#pragma unroll
    for (int off = 32; off > 0; off >>= 1) ss += __shfl_xor(ss, off, 64);
    float inv = 1.0f / fmaxf(sqrtf(ss), EPSN);
    float2 o; o.x = ax * inv + ca.x; o.y = ay * inv + ca.y;
    *reinterpret_cast<float2*>(out + base) = o;
}

__global__ void combine_all_kernel(const float* __restrict__ emb, const float* __restrict__ tball,
                                   float* __restrict__ b)
{
    int i = blockIdx.x * blockDim.x + threadIdx.x;
    const int n4 = NNODES * DIM / 4;
    if (i >= n4) return;
    int row = i >> 5;
    float t = tball[row] * (1.0f / 3.0f);
    float4 e  = reinterpret_cast<const float4*>(emb)[i];
    float4 bv = reinterpret_cast<float4*>(b)[i];
    bv.x = t * (e.x + bv.x); bv.y = t * (e.y + bv.y);
    bv.z = t * (e.z + bv.z); bv.w = t * (e.w + bv.w);
    reinterpret_cast<float4*>(b)[i] = bv;
}

__global__ void add_scaled_kernel(const float* __restrict__ a, const float* __restrict__ tbaux,
                                  float* __restrict__ b)
{
    int i = blockIdx.x * blockDim.x + threadIdx.x;
    const int n4 = NNODES * DIM / 4;
    if (i >= n4) return;
    int row = i >> 5;
    float t = tbaux[row] * (1.0f / 3.0f);
    float4 av = reinterpret_cast<const float4*>(a)[i];
    float4 bv = reinterpret_cast<float4*>(b)[i];
    bv.x += t * av.x; bv.y += t * av.y; bv.z += t * av.z; bv.w += t * av.w;
    reinterpret_cast<float4*>(b)[i] = bv;
}

// ===========================================================================
extern "C" void kernel_launch(void* const* d_in, const int* in_sizes, int n_in,
                              void* d_out, int out_size, void* d_ws, size_t ws_size,
                              hipStream_t stream)
{
    const float* emb       = (const float*)d_in[0];
    const int*   rows_aux  = (const int*)d_in[1];
    const int*   cols_aux  = (const int*)d_in[2];
    const float* vals_aux  = (const float*)d_in[3];
    const int*   rows_buy  = (const int*)d_in[4];
    const int*   cols_buy  = (const int*)d_in[5];
    const float* vals_buy  = (const float*)d_in[6];
    const float* t_aux_all = (const float*)d_in[7];
    const float* t_buy_all = (const float*)d_in[8];
    const float* t_buy_aux = (const float*)d_in[9];
    const int*   masks     = (const int*)d_in[10];   // numpy bool widened to int32

    float* out = (float*)d_out;
    const size_t nd = (size_t)NNODES * DIM;
    const size_t nd_bytes = nd * sizeof(float);

    // ---- workspace layout (16B-aligned regions) ----
    uint8_t* wsb = (uint8_t*)d_ws;
    size_t off = 0;
    auto carve = [&](size_t bytes) -> void* {
        void* p = wsb + off;
        off = (off + bytes + 15) & ~(size_t)15;
        return p;
    };
    const int SCAN_BLOCKS = (NNODES + 1023) / 1024;   // 147
    float* B0       = (float*)carve(nd_bytes);
    float* B1       = (float*)carve(nd_bytes);
    uint2* ent_aux  = (uint2*)carve((size_t)NEDGE * 8);
    uint2* ent_buy  = (uint2*)carve((size_t)NEDGE * 8);
    int*   rp_aux   = (int*)carve((NNODES + 1) * 4);
    int*   rp_buy   = (int*)carve((NNODES + 1) * 4);
    int*   cursor   = (int*)carve((NNODES + 1) * 4);
    int*   cnt      = (int*)carve((size_t)NNODES * 4);
    int*   partials = (int*)carve((size_t)SCAN_BLOCKS * 4);
    const bool use_csr = (off <= ws_size);

    const int EDGE_BLK  = 256;
    const int EDGE_GRID = (NEDGE + EDGE_BLK - 1) / EDGE_BLK;
    const int GROW_BLK  = 256;                      // 4 waves = 4 rows per block
    const int GROW_GRID = (NNODES + 3) / 4;

    if (use_csr) {
        // ---- CSR build: aux (mask bits 0..1), buy (mask bits 0..3 = global 2..5) ----
        hipMemsetAsync(cnt, 0, (size_t)NNODES * 4, stream);
        hist_kernel<<<EDGE_GRID, EDGE_BLK, 0, stream>>>(rows_aux, cnt);
        scan_phase1<<<SCAN_BLOCKS, 1024, 0, stream>>>(cnt, rp_aux, partials);
        scan_phase2<<<1, 256, 0, stream>>>(partials, SCAN_BLOCKS);
        scan_phase3<<<SCAN_BLOCKS, 1024, 0, stream>>>(rp_aux, partials, cursor);
        scatter_kernel<<<EDGE_GRID, EDGE_BLK, 0, stream>>>(rows_aux, cols_aux, vals_aux,
                                                           masks + 0 * (size_t)NEDGE, 2,
                                                           cursor, ent_aux);
        hipMemsetAsync(cnt, 0, (size_t)NNODES * 4, stream);
        hist_kernel<<<EDGE_GRID, EDGE_BLK, 0, stream>>>(rows_buy, cnt);
        scan_phase1<<<SCAN_BLOCKS, 1024, 0, stream>>>(cnt, rp_buy, partials);
        scan_phase2<<<1, 256, 0, stream>>>(partials, SCAN_BLOCKS);
        scan_phase3<<<SCAN_BLOCKS, 1024, 0, stream>>>(rp_buy, partials, cursor);
        scatter_kernel<<<EDGE_GRID, EDGE_BLK, 0, stream>>>(rows_buy, cols_buy, vals_buy,
                                                           masks + 2 * (size_t)NEDGE, 4,
                                                           cursor, ent_buy);

        // ---- Phase A: aux behavior ----
        gather_plain_kernel<<<GROW_GRID, GROW_BLK, 0, stream>>>(rp_aux, ent_aux, 0, emb, B0); // x1
        gather_fused_aux_kernel<<<GROW_GRID, GROW_BLK, 0, stream>>>(rp_aux, ent_aux, 1,
                                                                    B0, emb, t_aux_all, out); // cur_aux

        // ---- Phase B: buy behavior ----
        gather_plain_kernel<<<GROW_GRID, GROW_BLK, 0, stream>>>(rp_buy, ent_buy, 0, emb, B0); // b1
        gather_fused_lin_kernel<<<GROW_GRID, GROW_BLK, 0, stream>>>(rp_buy, ent_buy, 1,
                                                                    B0, emb, t_buy_all, B1);  // t*g_all
        gather_plain_kernel<<<GROW_GRID, GROW_BLK, 0, stream>>>(rp_buy, ent_buy, 2, out, B0); // a1
        gather_fused_final_kernel<<<GROW_GRID, GROW_BLK, 0, stream>>>(rp_buy, ent_buy, 3,
                                                                      B0, B1, t_buy_aux, out);
        return;
    }

    // ---- fallback: Round-3 atomic path ----
    const int SPMM_BLK  = 256;
    const int SPMM_GRID = (int)(((long long)NEDGE * 32 + SPMM_BLK - 1) / SPMM_BLK);
    const int ROW_BLK   = 256;
    const int ROW_GRID  = (NNODES * 64 + ROW_BLK - 1) / ROW_BLK;
    const int EW_BLK    = 256;
    const int EW_GRID   = (int)((nd / 4 + EW_BLK - 1) / EW_BLK);

    hipMemsetAsync(B0, 0, nd_bytes, stream);
    spmm_kernel<<<SPMM_GRID, SPMM_BLK, 0, stream>>>(rows_aux, cols_aux, vals_aux,
                                                    masks + 0 * (size_t)NEDGE, emb, B0);
    hipMemcpyAsync(B1, B0, nd_bytes, hipMemcpyDeviceToDevice, stream);
    spmm_kernel<<<SPMM_GRID, SPMM_BLK, 0, stream>>>(rows_aux, cols_aux, vals_aux,
                                                    masks + 1 * (size_t)NEDGE, B0, B1);
    rownorm_aux_kernel<<<ROW_GRID, ROW_BLK, 0, stream>>>(emb, B1, t_aux_all, out);

    hipMemsetAsync(B0, 0, nd_bytes, stream);
    spmm_kernel<<<SPMM_GRID, SPMM_BLK, 0, stream>>>(rows_buy, cols_buy, vals_buy,
                                                    masks + 2 * (size_t)NEDGE, emb, B0);
    hipMemcpyAsync(B1, B0, nd_bytes, hipMemcpyDeviceToDevice, stream);
    spmm_kernel<<<SPMM_GRID, SPMM_BLK, 0, stream>>>(rows_buy, cols_buy, vals_buy,
                                                    masks + 3 * (size_t)NEDGE, B0, B1);
    combine_all_kernel<<<EW_GRID, EW_BLK, 0, stream>>>(emb, t_buy_all, B1);

    hipMemsetAsync(B0, 0, nd_bytes, stream);
    spmm_kernel<<<SPMM_GRID, SPMM_BLK, 0, stream>>>(rows_buy, cols_buy, vals_buy,
                                                    masks + 4 * (size_t)NEDGE, out, B0);
    add_scaled_kernel<<<EW_GRID, EW_BLK, 0, stream>>>(B0, t_buy_aux, B1);
    spmm_scaled_kernel<<<SPMM_GRID, SPMM_BLK, 0, stream>>>(rows_buy, cols_buy, vals_buy,
                                                           masks + 5 * (size_t)NEDGE, B0, B1,
                                                           t_buy_aux);
    rownorm_final_kernel<<<ROW_GRID, ROW_BLK, 0, stream>>>(out, B1, t_buy_aux, out);
}

// Round 7
// 593.714 us; speedup vs baseline: 5.7267x; 1.1030x over previous
//
#include <hip/hip_runtime.h>
#include <cstdint>
#include <cstddef>

// Problem constants (match reference)
#define NNODES 150002      // N_USERS + N_ITEMS + 2
#define NN2    (2 * NNODES)
#define DIM    128
#define NEDGE  600000
#define EPSN   1e-12f

// ===========================================================================
// CSR-GATHER PATH: one concatenated CSR for both adjacencies
// (aux rows at [0,N), buy rows at [N,2N); entries at [0,E) and [E,2E)).
// Entry packing: 8 B/edge = { col | mask_bits<<24 , val }.
//   aux entry bits: bit0=masks[0], bit1=masks[1]
//   buy entry bits: bit0=masks[2], bit1=masks[3], bit2=masks[4], bit3=masks[5]
// Gather kernels: 32 lanes per row (float4/lane), 2 rows per wave.
// ===========================================================================

__global__ void hist_both(const int* __restrict__ ra,
                          const int* __restrict__ rb,
                          int* __restrict__ cnt)
{
    int e = blockIdx.x * blockDim.x + threadIdx.x;
    if (e < NEDGE)           atomicAdd(&cnt[ra[e]], 1);
    else if (e < 2 * NEDGE)  atomicAdd(&cnt[NNODES + rb[e - NEDGE]], 1);
}

// Phase 1: per-block exclusive scan of cnt (2N) -> rp (block-local), block sums -> partials
__global__ __launch_bounds__(1024)
void scan_phase1(const int* __restrict__ cnt,
                 int* __restrict__ local,
                 int* __restrict__ partials)
{
    __shared__ int lds[1024];
    int t = threadIdx.x;
    int i = blockIdx.x * 1024 + t;
    int v = (i < NN2) ? cnt[i] : 0;
    lds[t] = v;
    __syncthreads();
    for (int off = 1; off < 1024; off <<= 1) {
        int w = (t >= off) ? lds[t - off] : 0;
        __syncthreads();
        lds[t] += w;
        __syncthreads();
    }
    if (i < NN2) local[i] = lds[t] - v;
    if (t == 1023) partials[blockIdx.x] = lds[1023];
}

// Phase 2: single block exclusive-scans the partials (nparts <= 512)
__global__ __launch_bounds__(512)
void scan_phase2(int* __restrict__ partials, int nparts)
{
    __shared__ int lds[512];
    int t = threadIdx.x;
    int v = (t < nparts) ? partials[t] : 0;
    lds[t] = v;
    __syncthreads();
    for (int off = 1; off < 512; off <<= 1) {
        int w = (t >= off) ? lds[t - off] : 0;
        __syncthreads();
        lds[t] += w;
        __syncthreads();
    }
    if (t < nparts) partials[t] = lds[t] - v;
}

// Phase 3: add block offsets -> final rp + cursor copy; rp[2N] = 2E.
__global__ __launch_bounds__(1024)
void scan_phase3(int* __restrict__ rp,
                 const int* __restrict__ partials,
                 int* __restrict__ cursor)
{
    int i = blockIdx.x * 1024 + threadIdx.x;
    if (i >= NN2) return;
    int v = rp[i] + partials[blockIdx.x];
    rp[i] = v;
    cursor[i] = v;
    if (i == 0) rp[NN2] = 2 * NEDGE;
}

__global__ void scatter_both(const int* __restrict__ ra, const int* __restrict__ ca,
                             const float* __restrict__ va,
                             const int* __restrict__ rb, const int* __restrict__ cb,
                             const float* __restrict__ vb,
                             const int* __restrict__ masks,
                             int* __restrict__ cursor,
                             uint2* __restrict__ ent)
{
    int e = blockIdx.x * blockDim.x + threadIdx.x;
    if (e < NEDGE) {
        unsigned bits = (masks[e] != 0 ? 1u : 0u)
                      | (masks[(size_t)NEDGE + e] != 0 ? 2u : 0u);
        int pos = atomicAdd(&cursor[ra[e]], 1);
        ent[pos] = make_uint2((unsigned)ca[e] | (bits << 24), __float_as_uint(va[e]));
    } else if (e < 2 * NEDGE) {
        int e2 = e - NEDGE;
        unsigned bits = 0;
#pragma unroll
        for (int k = 0; k < 4; ++k)
            bits |= (masks[(size_t)(2 + k) * NEDGE + e2] != 0 ? 1u : 0u) << k;
        int pos = atomicAdd(&cursor[NNODES + rb[e2]], 1);
        ent[pos] = make_uint2((unsigned)cb[e2] | (bits << 24), __float_as_uint(vb[e2]));
    }
}

// ---------------------------------------------------------------------------
// Gather kernels: 32 lanes per row, float4 per lane.
// ---------------------------------------------------------------------------
#define G_SETUP                                                \
    int gid  = blockIdx.x * blockDim.x + threadIdx.x;          \
    int row  = gid >> 5;                                       \
    int lane = gid & 31;                                       \
    if (row >= NNODES) return;                                 \
    size_t base = (size_t)row * DIM + lane * 4;

#define FMA4(acc, v, xv)                                       \
    acc.x = fmaf(v, xv.x, acc.x);                              \
    acc.y = fmaf(v, xv.y, acc.y);                              \
    acc.z = fmaf(v, xv.z, acc.z);                              \
    acc.w = fmaf(v, xv.w, acc.w);

// aux layer 1: B0[row] = sum_{bit0} v * emb[col]
__global__ void aux1_kernel(const int* __restrict__ rp, const uint2* __restrict__ ent,
                            const float* __restrict__ emb, float* __restrict__ B0)
{
    G_SETUP
    int j0 = rp[row], j1 = rp[row + 1];
    float4 acc = make_float4(0.f, 0.f, 0.f, 0.f);
    for (int j = j0; j < j1; ++j) {
        uint2 E = ent[j];
        if (E.x & (1u << 24)) {
            float v = __uint_as_float(E.y);
            float4 xv = *reinterpret_cast<const float4*>(
                emb + (size_t)(E.x & 0xFFFFFFu) * DIM + lane * 4);
            FMA4(acc, v, xv)
        }
    }
    *reinterpret_cast<float4*>(B0 + base) = acc;
}

// aux layer 2 + epilogue: out = l2norm(t/3 * (emb + B0 + gather_bit1(B0))) + emb
__global__ void aux2_kernel(const int* __restrict__ rp, const uint2* __restrict__ ent,
                            const float* __restrict__ B0, const float* __restrict__ emb,
                            const float* __restrict__ trans, float* __restrict__ out)
{
    G_SETUP
    int j0 = rp[row], j1 = rp[row + 1];
    float4 acc = make_float4(0.f, 0.f, 0.f, 0.f);
    for (int j = j0; j < j1; ++j) {
        uint2 E = ent[j];
        if (E.x & (1u << 25)) {
            float v = __uint_as_float(E.y);
            float4 xv = *reinterpret_cast<const float4*>(
                B0 + (size_t)(E.x & 0xFFFFFFu) * DIM + lane * 4);
            FMA4(acc, v, xv)
        }
    }
    float t = trans[row] * (1.0f / 3.0f);
    float4 e = *reinterpret_cast<const float4*>(emb + base);
    float4 b = *reinterpret_cast<const float4*>(B0 + base);
    float4 a;
    a.x = t * (e.x + b.x + acc.x);
    a.y = t * (e.y + b.y + acc.y);
    a.z = t * (e.z + b.z + acc.z);
    a.w = t * (e.w + b.w + acc.w);
    float ss = a.x * a.x + a.y * a.y + a.z * a.z + a.w * a.w;
#pragma unroll
    for (int off = 16; off > 0; off >>= 1) ss += __shfl_xor(ss, off, 64);
    float inv = 1.0f / fmaxf(sqrtf(ss), EPSN);
    float4 o;
    o.x = a.x * inv + e.x;
    o.y = a.y * inv + e.y;
    o.z = a.z * inv + e.z;
    o.w = a.w * inv + e.w;
    *reinterpret_cast<float4*>(out + base) = o;
}

// buy layer 1 (fused g_all+g_aux): B0[row]=sum_{bit0} v*emb[col]; B1[row]=sum_{bit2} v*cur[col]
__global__ void buy1_kernel(const int* __restrict__ rp, const uint2* __restrict__ ent,
                            const float* __restrict__ emb, const float* __restrict__ cur,
                            float* __restrict__ B0, float* __restrict__ B1)
{
    G_SETUP
    int j0 = rp[row], j1 = rp[row + 1];
    float4 accA = make_float4(0.f, 0.f, 0.f, 0.f);
    float4 accX = make_float4(0.f, 0.f, 0.f, 0.f);
    for (int j = j0; j < j1; ++j) {
        uint2 E = ent[j];
        size_t cb = (size_t)(E.x & 0xFFFFFFu) * DIM + lane * 4;
        float v = __uint_as_float(E.y);
        if (E.x & (1u << 24)) {
            float4 xv = *reinterpret_cast<const float4*>(emb + cb);
            FMA4(accA, v, xv)
        }
        if (E.x & (1u << 26)) {
            float4 xv = *reinterpret_cast<const float4*>(cur + cb);
            FMA4(accX, v, xv)
        }
    }
    *reinterpret_cast<float4*>(B0 + base) = accA;
    *reinterpret_cast<float4*>(B1 + base) = accX;
}

// buy layer 2 + full epilogue:
// agg = tall/3*(emb+B0+gather_bit1(B0)) + taux/3*(cur+B1+gather_bit3(B1))
// out = l2norm(agg) + cur      (out aliases cur; row-local)
__global__ void buy2_kernel(const int* __restrict__ rp, const uint2* __restrict__ ent,
                            const float* __restrict__ B0, const float* __restrict__ B1,
                            const float* __restrict__ emb,
                            const float* __restrict__ tall, const float* __restrict__ taux,
                            float* __restrict__ out)
{
    G_SETUP
    int j0 = rp[row], j1 = rp[row + 1];
    float4 accA = make_float4(0.f, 0.f, 0.f, 0.f);
    float4 accX = make_float4(0.f, 0.f, 0.f, 0.f);
    for (int j = j0; j < j1; ++j) {
        uint2 E = ent[j];
        size_t cb = (size_t)(E.x & 0xFFFFFFu) * DIM + lane * 4;
        float v = __uint_as_float(E.y);
        if (E.x & (1u << 25)) {
            float4 xv = *reinterpret_cast<const float4*>(B0 + cb);
            FMA4(accA, v, xv)
        }
        if (E.x & (1u << 27)) {
            float4 xv = *reinterpret_cast<const float4*>(B1 + cb);
            FMA4(accX, v, xv)
        }
    }
    float ta = tall[row] * (1.0f / 3.0f);
    float tx = taux[row] * (1.0f / 3.0f);
    float4 e  = *reinterpret_cast<const float4*>(emb + base);
    float4 c  = *reinterpret_cast<const float4*>(out + base);
    float4 b0 = *reinterpret_cast<const float4*>(B0 + base);
    float4 b1 = *reinterpret_cast<const float4*>(B1 + base);
    float4 a;
    a.x = ta * (e.x + b0.x + accA.x) + tx * (c.x + b1.x + accX.x);
    a.y = ta * (e.y + b0.y + accA.y) + tx * (c.y + b1.y + accX.y);
    a.z = ta * (e.z + b0.z + accA.z) + tx * (c.z + b1.z + accX.z);
    a.w = ta * (e.w + b0.w + accA.w) + tx * (c.w + b1.w + accX.w);
    float ss = a.x * a.x + a.y * a.y + a.z * a.z + a.w * a.w;
#pragma unroll
    for (int off = 16; off > 0; off >>= 1) ss += __shfl_xor(ss, off, 64);
    float inv = 1.0f / fmaxf(sqrtf(ss), EPSN);
    float4 o;
    o.x = a.x * inv + c.x;
    o.y = a.y * inv + c.y;
    o.z = a.z * inv + c.z;
    o.w = a.w * inv + c.w;
    *reinterpret_cast<float4*>(out + base) = o;
}

// ===========================================================================
// FALLBACK PATH (Round-3 proven atomic scatter) — used only if ws too small.
// ===========================================================================
__global__ void spmm_kernel(const int* __restrict__ rows, const int* __restrict__ cols,
                            const float* __restrict__ vals, const int* __restrict__ mask,
                            const float* __restrict__ x, float* __restrict__ y)
{
    long long gid = (long long)blockIdx.x * blockDim.x + threadIdx.x;
    int e = (int)(gid >> 5); int lane = (int)(gid & 31);
    if (e >= NEDGE) return;
    if (!mask[e]) return;
    float v = vals[e]; int c = cols[e]; int r = rows[e];
    float4 xv = *reinterpret_cast<const float4*>(x + (size_t)c * DIM + lane * 4);
    float* dst = y + (size_t)r * DIM + lane * 4;
    atomicAdd(dst + 0, v * xv.x); atomicAdd(dst + 1, v * xv.y);
    atomicAdd(dst + 2, v * xv.z); atomicAdd(dst + 3, v * xv.w);
}

__global__ void spmm_scaled_kernel(const int* __restrict__ rows, const int* __restrict__ cols,
                                   const float* __restrict__ vals, const int* __restrict__ mask,
                                   const float* __restrict__ x, float* __restrict__ y,
                                   const float* __restrict__ rowscale)
{
    long long gid = (long long)blockIdx.x * blockDim.x + threadIdx.x;
    int e = (int)(gid >> 5); int lane = (int)(gid & 31);
    if (e >= NEDGE) return;
    if (!mask[e]) return;
    int r = rows[e];
    float v = vals[e] * rowscale[r] * (1.0f / 3.0f);
    int c = cols[e];
    float4 xv = *reinterpret_cast<const float4*>(x + (size_t)c * DIM + lane * 4);
    float* dst = y + (size_t)r * DIM + lane * 4;
    atomicAdd(dst + 0, v * xv.x); atomicAdd(dst + 1, v * xv.y);
    atomicAdd(dst + 2, v * xv.z); atomicAdd(dst + 3, v * xv.w);
}

__global__ void rownorm_aux_kernel(const float* __restrict__ emb, const float* __restrict__ s,
                                   const float* __restrict__ trans, float* __restrict__ out)
{
    int gid = blockIdx.x * blockDim.x + threadIdx.x;
    int row = gid >> 6; int lane = gid & 63;
    if (row >= NNODES) return;
    float t = trans[row] * (1.0f / 3.0f);
    size_t base = (size_t)row * DIM + lane * 2;
    float2 e  = *reinterpret_cast<const float2*>(emb + base);
    float2 sv = *reinterpret_cast<const float2*>(s + base);
    float ax = t * (e.x + sv.x); float ay = t * (e.y + sv.y);
    float ss = ax * ax + ay * ay;
#pragma unroll
    for (int off = 32; off > 0; off >>= 1) ss += __shfl_xor(ss, off, 64);
    float inv = 1.0f / fmaxf(sqrtf(ss), EPSN);
    float2 o; o.x = ax * inv + e.x; o.y = ay * inv + e.y;
    *reinterpret_cast<float2*>(out + base) = o;
}

__global__ void rownorm_final_kernel(const float* __restrict__ cur_aux, const float* __restrict__ b,
                                     const float* __restrict__ tbaux, float* __restrict__ out)
{
    int gid = blockIdx.x * blockDim.x + threadIdx.x;
    int row = gid >> 6; int lane = gid & 63;
    if (row >= NNODES) return;
    float t = tbaux[row] * (1.0f / 3.0f);
    size_t base = (size_t)row * DIM + lane * 2;
    float2 ca = *reinterpret_cast<const float2*>(cur_aux + base);
    float2 bv = *reinterpret_cast<const float2*>(b + base);
    float ax = bv.x + t * ca.x; float ay = bv.y + t * ca.y;
    float ss = ax * ax + ay * ay;
#pragma unroll
    for (int off = 32; off > 0; off >>= 1) ss += __shfl_xor(ss, off, 64);
    float inv = 1.0f / fmaxf(sqrtf(ss), EPSN);
    float2 o; o.x = ax * inv + ca.x; o.y = ay * inv + ca.y;
    *reinterpret_cast<float2*>(out + base) = o;
}

__global__ void combine_all_kernel(const float* __restrict__ emb, const float* __restrict__ tball,
                                   float* __restrict__ b)
{
    int i = blockIdx.x * blockDim.x + threadIdx.x;
    const int n4 = NNODES * DIM / 4;
    if (i >= n4) return;
    int row = i >> 5;
    float t = tball[row] * (1.0f / 3.0f);
    float4 e  = reinterpret_cast<const float4*>(emb)[i];
    float4 bv = reinterpret_cast<float4*>(b)[i];
    bv.x = t * (e.x + bv.x); bv.y = t * (e.y + bv.y);
    bv.z = t * (e.z + bv.z); bv.w = t * (e.w + bv.w);
    reinterpret_cast<float4*>(b)[i] = bv;
}

__global__ void add_scaled_kernel(const float* __restrict__ a, const float* __restrict__ tbaux,
                                  float* __restrict__ b)
{
    int i = blockIdx.x * blockDim.x + threadIdx.x;
    const int n4 = NNODES * DIM / 4;
    if (i >= n4) return;
    int row = i >> 5;
    float t = tbaux[row] * (1.0f / 3.0f);
    float4 av = reinterpret_cast<const float4*>(a)[i];
    float4 bv = reinterpret_cast<float4*>(b)[i];
    bv.x += t * av.x; bv.y += t * av.y; bv.z += t * av.z; bv.w += t * av.w;
    reinterpret_cast<float4*>(b)[i] = bv;
}

// ===========================================================================
extern "C" void kernel_launch(void* const* d_in, const int* in_sizes, int n_in,
                              void* d_out, int out_size, void* d_ws, size_t ws_size,
                              hipStream_t stream)
{
    const float* emb       = (const float*)d_in[0];
    const int*   rows_aux  = (const int*)d_in[1];
    const int*   cols_aux  = (const int*)d_in[2];
    const float* vals_aux  = (const float*)d_in[3];
    const int*   rows_buy  = (const int*)d_in[4];
    const int*   cols_buy  = (const int*)d_in[5];
    const float* vals_buy  = (const float*)d_in[6];
    const float* t_aux_all = (const float*)d_in[7];
    const float* t_buy_all = (const float*)d_in[8];
    const float* t_buy_aux = (const float*)d_in[9];
    const int*   masks     = (const int*)d_in[10];   // numpy bool widened to int32

    float* out = (float*)d_out;
    const size_t nd = (size_t)NNODES * DIM;
    const size_t nd_bytes = nd * sizeof(float);

    // ---- workspace layout (16B-aligned regions) ----
    uint8_t* wsb = (uint8_t*)d_ws;
    size_t off = 0;
    auto carve = [&](size_t bytes) -> void* {
        void* p = wsb + off;
        off = (off + bytes + 15) & ~(size_t)15;
        return p;
    };
    const int SCAN_BLOCKS = (NN2 + 1023) / 1024;   // 294
    float* B0       = (float*)carve(nd_bytes);
    float* B1       = (float*)carve(nd_bytes);
    uint2* ent      = (uint2*)carve((size_t)2 * NEDGE * 8);
    int*   rp       = (int*)carve(((size_t)NN2 + 1) * 4);
    int*   cursor   = (int*)carve((size_t)NN2 * 4);
    int*   cnt      = (int*)carve((size_t)NN2 * 4);
    int*   partials = (int*)carve((size_t)SCAN_BLOCKS * 4);
    const bool use_csr = (off <= ws_size);

    if (use_csr) {
        const int EB   = 256;
        const int EG2  = (2 * NEDGE + EB - 1) / EB;
        const int GB   = 256;                       // 8 rows/block (32 lanes/row)
        const int GG   = (NNODES * 32 + GB - 1) / GB;

        // ---- CSR build (both adjacencies in one pass) ----
        hipMemsetAsync(cnt, 0, (size_t)NN2 * 4, stream);
        hist_both<<<EG2, EB, 0, stream>>>(rows_aux, rows_buy, cnt);
        scan_phase1<<<SCAN_BLOCKS, 1024, 0, stream>>>(cnt, rp, partials);
        scan_phase2<<<1, 512, 0, stream>>>(partials, SCAN_BLOCKS);
        scan_phase3<<<SCAN_BLOCKS, 1024, 0, stream>>>(rp, partials, cursor);
        scatter_both<<<EG2, EB, 0, stream>>>(rows_aux, cols_aux, vals_aux,
                                             rows_buy, cols_buy, vals_buy,
                                             masks, cursor, ent);

        // ---- Phase A: aux behavior ----
        aux1_kernel<<<GG, GB, 0, stream>>>(rp, ent, emb, B0);
        aux2_kernel<<<GG, GB, 0, stream>>>(rp, ent, B0, emb, t_aux_all, out);

        // ---- Phase B: buy behavior (fused) ----
        buy1_kernel<<<GG, GB, 0, stream>>>(rp + NNODES, ent, emb, out, B0, B1);
        buy2_kernel<<<GG, GB, 0, stream>>>(rp + NNODES, ent, B0, B1, emb,
                                           t_buy_all, t_buy_aux, out);
        return;
    }

    // ---- fallback: Round-3 atomic path ----
    const int SPMM_BLK  = 256;
    const int SPMM_GRID = (int)(((long long)NEDGE * 32 + SPMM_BLK - 1) / SPMM_BLK);
    const int ROW_BLK   = 256;
    const int ROW_GRID  = (NNODES * 64 + ROW_BLK - 1) / ROW_BLK;
    const int EW_BLK    = 256;
    const int EW_GRID   = (int)((nd / 4 + EW_BLK - 1) / EW_BLK);

    hipMemsetAsync(B0, 0, nd_bytes, stream);
    spmm_kernel<<<SPMM_GRID, SPMM_BLK, 0, stream>>>(rows_aux, cols_aux, vals_aux,
                                                    masks + 0 * (size_t)NEDGE, emb, B0);
    hipMemcpyAsync(B1, B0, nd_bytes, hipMemcpyDeviceToDevice, stream);
    spmm_kernel<<<SPMM_GRID, SPMM_BLK, 0, stream>>>(rows_aux, cols_aux, vals_aux,
                                                    masks + 1 * (size_t)NEDGE, B0, B1);
    rownorm_aux_kernel<<<ROW_GRID, ROW_BLK, 0, stream>>>(emb, B1, t_aux_all, out);

    hipMemsetAsync(B0, 0, nd_bytes, stream);
    spmm_kernel<<<SPMM_GRID, SPMM_BLK, 0, stream>>>(rows_buy, cols_buy, vals_buy,
                                                    masks + 2 * (size_t)NEDGE, emb, B0);
    hipMemcpyAsync(B1, B0, nd_bytes, hipMemcpyDeviceToDevice, stream);
    spmm_kernel<<<SPMM_GRID, SPMM_BLK, 0, stream>>>(rows_buy, cols_buy, vals_buy,
                                                    masks + 3 * (size_t)NEDGE, B0, B1);
    combine_all_kernel<<<EW_GRID, EW_BLK, 0, stream>>>(emb, t_buy_all, B1);

    hipMemsetAsync(B0, 0, nd_bytes, stream);
    spmm_kernel<<<SPMM_GRID, SPMM_BLK, 0, stream>>>(rows_buy, cols_buy, vals_buy,
                                                    masks + 4 * (size_t)NEDGE, out, B0);
    add_scaled_kernel<<<EW_GRID, EW_BLK, 0, stream>>>(B0, t_buy_aux, B1);
    spmm_scaled_kernel<<<SPMM_GRID, SPMM_BLK, 0, stream>>>(rows_buy, cols_buy, vals_buy,
                                                           masks + 5 * (size_t)NEDGE, B0, B1,
                                                           t_buy_aux);
    rownorm_final_kernel<<<ROW_GRID, ROW_BLK, 0, stream>>>(out, B1, t_buy_aux, out);
}

// Round 8
// 531.085 us; speedup vs baseline: 6.4021x; 1.1179x over previous
//
#include <hip/hip_runtime.h>
#include <cstdint>
#include <cstddef>

// Problem constants (match reference)
#define NNODES 150002      // N_USERS + N_ITEMS + 2
#define NN2    (2 * NNODES)
#define DIM    128
#define NEDGE  600000
#define EPSN   1e-12f

// ===========================================================================
// CSR-GATHER PATH: one concatenated CSR for both adjacencies
// (aux rows at [0,N), buy rows at [N,2N); entries at [0,E) and [E,2E)).
// Entry packing: 8 B/edge = { col | mask_bits<<24 , val }.
//   aux entry bits: bit0=masks[0], bit1=masks[1]
//   buy entry bits: bit0=masks[2], bit1=masks[3], bit2=masks[4], bit3=masks[5]
// Gather kernels: 16 lanes per row (2x float4 per lane), 4 rows per wave,
// entry loop unrolled x2 so up to 4-8 gather loads are in flight per group
// (the Round-7 profile showed latency-bound gathers at 3.4 TB/s, VGPR=20).
// ===========================================================================

__global__ void hist_both(const int* __restrict__ ra,
                          const int* __restrict__ rb,
                          int* __restrict__ cnt)
{
    int e = blockIdx.x * blockDim.x + threadIdx.x;
    if (e < NEDGE)           atomicAdd(&cnt[ra[e]], 1);
    else if (e < 2 * NEDGE)  atomicAdd(&cnt[NNODES + rb[e - NEDGE]], 1);
}

__global__ __launch_bounds__(1024)
void scan_phase1(const int* __restrict__ cnt,
                 int* __restrict__ local,
                 int* __restrict__ partials)
{
    __shared__ int lds[1024];
    int t = threadIdx.x;
    int i = blockIdx.x * 1024 + t;
    int v = (i < NN2) ? cnt[i] : 0;
    lds[t] = v;
    __syncthreads();
    for (int off = 1; off < 1024; off <<= 1) {
        int w = (t >= off) ? lds[t - off] : 0;
        __syncthreads();
        lds[t] += w;
        __syncthreads();
    }
    if (i < NN2) local[i] = lds[t] - v;
    if (t == 1023) partials[blockIdx.x] = lds[1023];
}

__global__ __launch_bounds__(512)
void scan_phase2(int* __restrict__ partials, int nparts)
{
    __shared__ int lds[512];
    int t = threadIdx.x;
    int v = (t < nparts) ? partials[t] : 0;
    lds[t] = v;
    __syncthreads();
    for (int off = 1; off < 512; off <<= 1) {
        int w = (t >= off) ? lds[t - off] : 0;
        __syncthreads();
        lds[t] += w;
        __syncthreads();
    }
    if (t < nparts) partials[t] = lds[t] - v;
}

__global__ __launch_bounds__(1024)
void scan_phase3(int* __restrict__ rp,
                 const int* __restrict__ partials,
                 int* __restrict__ cursor)
{
    int i = blockIdx.x * 1024 + threadIdx.x;
    if (i >= NN2) return;
    int v = rp[i] + partials[blockIdx.x];
    rp[i] = v;
    cursor[i] = v;
    if (i == 0) rp[NN2] = 2 * NEDGE;
}

__global__ void scatter_both(const int* __restrict__ ra, const int* __restrict__ ca,
                             const float* __restrict__ va,
                             const int* __restrict__ rb, const int* __restrict__ cb,
                             const float* __restrict__ vb,
                             const int* __restrict__ masks,
                             int* __restrict__ cursor,
                             uint2* __restrict__ ent)
{
    int e = blockIdx.x * blockDim.x + threadIdx.x;
    if (e < NEDGE) {
        unsigned bits = (masks[e] != 0 ? 1u : 0u)
                      | (masks[(size_t)NEDGE + e] != 0 ? 2u : 0u);
        int pos = atomicAdd(&cursor[ra[e]], 1);
        ent[pos] = make_uint2((unsigned)ca[e] | (bits << 24), __float_as_uint(va[e]));
    } else if (e < 2 * NEDGE) {
        int e2 = e - NEDGE;
        unsigned bits = 0;
#pragma unroll
        for (int k = 0; k < 4; ++k)
            bits |= (masks[(size_t)(2 + k) * NEDGE + e2] != 0 ? 1u : 0u) << k;
        int pos = atomicAdd(&cursor[NNODES + rb[e2]], 1);
        ent[pos] = make_uint2((unsigned)cb[e2] | (bits << 24), __float_as_uint(vb[e2]));
    }
}

// ---------------------------------------------------------------------------
// Gather kernels: 16 lanes per row; lane covers floats [lane*4, lane*4+4) and
// [64+lane*4, 64+lane*4+4) of the 128-wide row (two coalesced 256B requests).
// ---------------------------------------------------------------------------
#define G16_SETUP                                              \
    int gid  = blockIdx.x * blockDim.x + threadIdx.x;          \
    int row  = gid >> 4;                                       \
    int lane = gid & 15;                                       \
    if (row >= NNODES) return;                                 \
    size_t base = (size_t)row * DIM + lane * 4;   /* hi at base+64 */

#define FMA4(acc, v, xv)                                       \
    acc.x = fmaf(v, xv.x, acc.x);                              \
    acc.y = fmaf(v, xv.y, acc.y);                              \
    acc.z = fmaf(v, xv.z, acc.z);                              \
    acc.w = fmaf(v, xv.w, acc.w);

#define ADD4(a, b) a.x += b.x; a.y += b.y; a.z += b.z; a.w += b.w;

// Single-source gather (mask bit bm), unroll x2.
__device__ __forceinline__ void gather16_1(const int* __restrict__ rp,
                                           const uint2* __restrict__ ent,
                                           unsigned bm, int row, int lane,
                                           const float* __restrict__ x,
                                           float4& alo, float4& ahi)
{
    int j0 = rp[row], j1 = rp[row + 1];
    float4 l0 = {0,0,0,0}, h0 = {0,0,0,0}, l1 = {0,0,0,0}, h1 = {0,0,0,0};
    int j = j0;
    for (; j + 2 <= j1; j += 2) {
        uint2 Ea = ent[j], Eb = ent[j + 1];
        bool ma = (Ea.x & bm) != 0, mb = (Eb.x & bm) != 0;
        const float* pa = x + (size_t)(Ea.x & 0xFFFFFFu) * DIM + lane * 4;
        const float* pb = x + (size_t)(Eb.x & 0xFFFFFFu) * DIM + lane * 4;
        float4 xla, xha, xlb, xhb;
        if (ma) { xla = *(const float4*)pa;        xha = *(const float4*)(pa + 64); }
        if (mb) { xlb = *(const float4*)pb;        xhb = *(const float4*)(pb + 64); }
        if (ma) { float v = __uint_as_float(Ea.y); FMA4(l0, v, xla) FMA4(h0, v, xha) }
        if (mb) { float v = __uint_as_float(Eb.y); FMA4(l1, v, xlb) FMA4(h1, v, xhb) }
    }
    if (j < j1) {
        uint2 E = ent[j];
        if ((E.x & bm) != 0) {
            const float* p = x + (size_t)(E.x & 0xFFFFFFu) * DIM + lane * 4;
            float v = __uint_as_float(E.y);
            float4 xl = *(const float4*)p, xh = *(const float4*)(p + 64);
            FMA4(l0, v, xl) FMA4(h0, v, xh)
        }
    }
    ADD4(l0, l1) ADD4(h0, h1)
    alo = l0; ahi = h0;
}

// Dual-source gather (xA on bit bmA, xB on bit bmB), unroll x2.
__device__ __forceinline__ void gather16_2(const int* __restrict__ rp,
                                           const uint2* __restrict__ ent,
                                           int row, int lane,
                                           const float* __restrict__ xA, unsigned bmA,
                                           const float* __restrict__ xB, unsigned bmB,
                                           float4& Alo, float4& Ahi,
                                           float4& Blo, float4& Bhi)
{
    int j0 = rp[row], j1 = rp[row + 1];
    float4 al0 = {0,0,0,0}, ah0 = {0,0,0,0}, al1 = {0,0,0,0}, ah1 = {0,0,0,0};
    float4 bl0 = {0,0,0,0}, bh0 = {0,0,0,0}, bl1 = {0,0,0,0}, bh1 = {0,0,0,0};
    int j = j0;
    for (; j + 2 <= j1; j += 2) {
        uint2 Ea = ent[j], Eb = ent[j + 1];
        size_t ca = (size_t)(Ea.x & 0xFFFFFFu) * DIM + lane * 4;
        size_t cb = (size_t)(Eb.x & 0xFFFFFFu) * DIM + lane * 4;
        bool maA = (Ea.x & bmA) != 0, maB = (Ea.x & bmB) != 0;
        bool mbA = (Eb.x & bmA) != 0, mbB = (Eb.x & bmB) != 0;
        float4 xaAl, xaAh, xaBl, xaBh, xbAl, xbAh, xbBl, xbBh;
        if (maA) { xaAl = *(const float4*)(xA + ca); xaAh = *(const float4*)(xA + ca + 64); }
        if (maB) { xaBl = *(const float4*)(xB + ca); xaBh = *(const float4*)(xB + ca + 64); }
        if (mbA) { xbAl = *(const float4*)(xA + cb); xbAh = *(const float4*)(xA + cb + 64); }
        if (mbB) { xbBl = *(const float4*)(xB + cb); xbBh = *(const float4*)(xB + cb + 64); }
        float va = __uint_as_float(Ea.y), vb = __uint_as_float(Eb.y);
        if (maA) { FMA4(al0, va, xaAl) FMA4(ah0, va, xaAh) }
        if (maB) { FMA4(bl0, va, xaBl) FMA4(bh0, va, xaBh) }
        if (mbA) { FMA4(al1, vb, xbAl) FMA4(ah1, vb, xbAh) }
        if (mbB) { FMA4(bl1, vb, xbBl) FMA4(bh1, vb, xbBh) }
    }
    if (j < j1) {
        uint2 E = ent[j];
        size_t cc = (size_t)(E.x & 0xFFFFFFu) * DIM + lane * 4;
        bool mA = (E.x & bmA) != 0, mB = (E.x & bmB) != 0;
        float4 xAl, xAh, xBl, xBh;
        if (mA) { xAl = *(const float4*)(xA + cc); xAh = *(const float4*)(xA + cc + 64); }
        if (mB) { xBl = *(const float4*)(xB + cc); xBh = *(const float4*)(xB + cc + 64); }
        float v = __uint_as_float(E.y);
        if (mA) { FMA4(al0, v, xAl) FMA4(ah0, v, xAh) }
        if (mB) { FMA4(bl0, v, xBl) FMA4(bh0, v, xBh) }
    }
    ADD4(al0, al1) ADD4(ah0, ah1) ADD4(bl0, bl1) ADD4(bh0, bh1)
    Alo = al0; Ahi = ah0; Blo = bl0; Bhi = bh0;
}

// aux layer 1: B0[row] = sum_{bit0} v * emb[col]
__global__ void aux1_kernel(const int* __restrict__ rp, const uint2* __restrict__ ent,
                            const float* __restrict__ emb, float* __restrict__ B0)
{
    G16_SETUP
    float4 alo, ahi;
    gather16_1(rp, ent, 1u << 24, row, lane, emb, alo, ahi);
    *reinterpret_cast<float4*>(B0 + base)      = alo;
    *reinterpret_cast<float4*>(B0 + base + 64) = ahi;
}

// aux layer 2 + epilogue: out = l2norm(t/3 * (emb + B0 + gather_bit1(B0))) + emb
__global__ void aux2_kernel(const int* __restrict__ rp, const uint2* __restrict__ ent,
                            const float* __restrict__ B0, const float* __restrict__ emb,
                            const float* __restrict__ trans, float* __restrict__ out)
{
    G16_SETUP
    float4 alo, ahi;
    gather16_1(rp, ent, 1u << 25, row, lane, B0, alo, ahi);
    float t = trans[row] * (1.0f / 3.0f);
    float4 elo = *reinterpret_cast<const float4*>(emb + base);
    float4 ehi = *reinterpret_cast<const float4*>(emb + base + 64);
    float4 blo = *reinterpret_cast<const float4*>(B0 + base);
    float4 bhi = *reinterpret_cast<const float4*>(B0 + base + 64);
    float4 lo, hi;
    lo.x = t * (elo.x + blo.x + alo.x); lo.y = t * (elo.y + blo.y + alo.y);
    lo.z = t * (elo.z + blo.z + alo.z); lo.w = t * (elo.w + blo.w + alo.w);
    hi.x = t * (ehi.x + bhi.x + ahi.x); hi.y = t * (ehi.y + bhi.y + ahi.y);
    hi.z = t * (ehi.z + bhi.z + ahi.z); hi.w = t * (ehi.w + bhi.w + ahi.w);
    float ss = lo.x*lo.x + lo.y*lo.y + lo.z*lo.z + lo.w*lo.w
             + hi.x*hi.x + hi.y*hi.y + hi.z*hi.z + hi.w*hi.w;
#pragma unroll
    for (int off = 8; off > 0; off >>= 1) ss += __shfl_xor(ss, off, 64);
    float inv = 1.0f / fmaxf(sqrtf(ss), EPSN);
    float4 olo, ohi;
    olo.x = lo.x * inv + elo.x; olo.y = lo.y * inv + elo.y;
    olo.z = lo.z * inv + elo.z; olo.w = lo.w * inv + elo.w;
    ohi.x = hi.x * inv + ehi.x; ohi.y = hi.y * inv + ehi.y;
    ohi.z = hi.z * inv + ehi.z; ohi.w = hi.w * inv + ehi.w;
    *reinterpret_cast<float4*>(out + base)      = olo;
    *reinterpret_cast<float4*>(out + base + 64) = ohi;
}

// buy layer 1 (fused g_all+g_aux): B0[row]=sum_{bit0} v*emb[col]; B1[row]=sum_{bit2} v*cur[col]
__global__ void buy1_kernel(const int* __restrict__ rp, const uint2* __restrict__ ent,
                            const float* __restrict__ emb, const float* __restrict__ cur,
                            float* __restrict__ B0, float* __restrict__ B1)
{
    G16_SETUP
    float4 Alo, Ahi, Xlo, Xhi;
    gather16_2(rp, ent, row, lane, emb, 1u << 24, cur, 1u << 26, Alo, Ahi, Xlo, Xhi);
    *reinterpret_cast<float4*>(B0 + base)      = Alo;
    *reinterpret_cast<float4*>(B0 + base + 64) = Ahi;
    *reinterpret_cast<float4*>(B1 + base)      = Xlo;
    *reinterpret_cast<float4*>(B1 + base + 64) = Xhi;
}

// buy layer 2 + full epilogue:
// agg = tall/3*(emb+B0+gather_bit1(B0)) + taux/3*(cur+B1+gather_bit3(B1))
// out = l2norm(agg) + cur      (out aliases cur; row-local)
__global__ void buy2_kernel(const int* __restrict__ rp, const uint2* __restrict__ ent,
                            const float* __restrict__ B0, const float* __restrict__ B1,
                            const float* __restrict__ emb,
                            const float* __restrict__ tall, const float* __restrict__ taux,
                            float* __restrict__ out)
{
    G16_SETUP
    float4 Alo, Ahi, Xlo, Xhi;
    gather16_2(rp, ent, row, lane, B0, 1u << 25, B1, 1u << 27, Alo, Ahi, Xlo, Xhi);
    float ta = tall[row] * (1.0f / 3.0f);
    float tx = taux[row] * (1.0f / 3.0f);
    float4 elo = *reinterpret_cast<const float4*>(emb + base);
    float4 ehi = *reinterpret_cast<const float4*>(emb + base + 64);
    float4 clo = *reinterpret_cast<const float4*>(out + base);
    float4 chi = *reinterpret_cast<const float4*>(out + base + 64);
    float4 b0lo = *reinterpret_cast<const float4*>(B0 + base);
    float4 b0hi = *reinterpret_cast<const float4*>(B0 + base + 64);
    float4 b1lo = *reinterpret_cast<const float4*>(B1 + base);
    float4 b1hi = *reinterpret_cast<const float4*>(B1 + base + 64);
    float4 lo, hi;
    lo.x = ta * (elo.x + b0lo.x + Alo.x) + tx * (clo.x + b1lo.x + Xlo.x);
    lo.y = ta * (elo.y + b0lo.y + Alo.y) + tx * (clo.y + b1lo.y + Xlo.y);
    lo.z = ta * (elo.z + b0lo.z + Alo.z) + tx * (clo.z + b1lo.z + Xlo.z);
    lo.w = ta * (elo.w + b0lo.w + Alo.w) + tx * (clo.w + b1lo.w + Xlo.w);
    hi.x = ta * (ehi.x + b0hi.x + Ahi.x) + tx * (chi.x + b1hi.x + Xhi.x);
    hi.y = ta * (ehi.y + b0hi.y + Ahi.y) + tx * (chi.y + b1hi.y + Xhi.y);
    hi.z = ta * (ehi.z + b0hi.z + Ahi.z) + tx * (chi.z + b1hi.z + Xhi.z);
    hi.w = ta * (ehi.w + b0hi.w + Ahi.w) + tx * (chi.w + b1hi.w + Xhi.w);
    float ss = lo.x*lo.x + lo.y*lo.y + lo.z*lo.z + lo.w*lo.w
             + hi.x*hi.x + hi.y*hi.y + hi.z*hi.z + hi.w*hi.w;
#pragma unroll
    for (int off = 8; off > 0; off >>= 1) ss += __shfl_xor(ss, off, 64);
    float inv = 1.0f / fmaxf(sqrtf(ss), EPSN);
    float4 olo, ohi;
    olo.x = lo.x * inv + clo.x; olo.y = lo.y * inv + clo.y;
    olo.z = lo.z * inv + clo.z; olo.w = lo.w * inv + clo.w;
    ohi.x = hi.x * inv + chi.x; ohi.y = hi.y * inv + chi.y;
    ohi.z = hi.z * inv + chi.z; ohi.w = hi.w * inv + chi.w;
    *reinterpret_cast<float4*>(out + base)      = olo;
    *reinterpret_cast<float4*>(out + base + 64) = ohi;
}

// ===========================================================================
// FALLBACK PATH (Round-3 proven atomic scatter) — used only if ws too small.
// ===========================================================================
__global__ void spmm_kernel(const int* __restrict__ rows, const int* __restrict__ cols,
                            const float* __restrict__ vals, const int* __restrict__ mask,
                            const float* __restrict__ x, float* __restrict__ y)
{
    long long gid = (long long)blockIdx.x * blockDim.x + threadIdx.x;
    int e = (int)(gid >> 5); int lane = (int)(gid & 31);
    if (e >= NEDGE) return;
    if (!mask[e]) return;
    float v = vals[e]; int c = cols[e]; int r = rows[e];
    float4 xv = *reinterpret_cast<const float4*>(x + (size_t)c * DIM + lane * 4);
    float* dst = y + (size_t)r * DIM + lane * 4;
    atomicAdd(dst + 0, v * xv.x); atomicAdd(dst + 1, v * xv.y);
    atomicAdd(dst + 2, v * xv.z); atomicAdd(dst + 3, v * xv.w);
}

__global__ void spmm_scaled_kernel(const int* __restrict__ rows, const int* __restrict__ cols,
                                   const float* __restrict__ vals, const int* __restrict__ mask,
                                   const float* __restrict__ x, float* __restrict__ y,
                                   const float* __restrict__ rowscale)
{
    long long gid = (long long)blockIdx.x * blockDim.x + threadIdx.x;
    int e = (int)(gid >> 5); int lane = (int)(gid & 31);
    if (e >= NEDGE) return;
    if (!mask[e]) return;
    int r = rows[e];
    float v = vals[e] * rowscale[r] * (1.0f / 3.0f);
    int c = cols[e];
    float4 xv = *reinterpret_cast<const float4*>(x + (size_t)c * DIM + lane * 4);
    float* dst = y + (size_t)r * DIM + lane * 4;
    atomicAdd(dst + 0, v * xv.x); atomicAdd(dst + 1, v * xv.y);
    atomicAdd(dst + 2, v * xv.z); atomicAdd(dst + 3, v * xv.w);
}

__global__ void rownorm_aux_kernel(const float* __restrict__ emb, const float* __restrict__ s,
                                   const float* __restrict__ trans, float* __restrict__ out)
{
    int gid = blockIdx.x * blockDim.x + threadIdx.x;
    int row = gid >> 6; int lane = gid & 63;
    if (row >= NNODES) return;
    float t = trans[row] * (1.0f / 3.0f);
    size_t base = (size_t)row * DIM + lane * 2;
    float2 e  = *reinterpret_cast<const float2*>(emb + base);
    float2 sv = *reinterpret_cast<const float2*>(s + base);
    float ax = t * (e.x + sv.x); float ay = t * (e.y + sv.y);
    float ss = ax * ax + ay * ay;
#pragma unroll
    for (int off = 32; off > 0; off >>= 1) ss += __shfl_xor(ss, off, 64);
    float inv = 1.0f / fmaxf(sqrtf(ss), EPSN);
    float2 o; o.x = ax * inv + e.x; o.y = ay * inv + e.y;
    *reinterpret_cast<float2*>(out + base) = o;
}

__global__ void rownorm_final_kernel(const float* __restrict__ cur_aux, const float* __restrict__ b,
                                     const float* __restrict__ tbaux, float* __restrict__ out)
{
    int gid = blockIdx.x * blockDim.x + threadIdx.x;
    int row = gid >> 6; int lane = gid & 63;
    if (row >= NNODES) return;
    float t = tbaux[row] * (1.0f / 3.0f);
    size_t base = (size_t)row * DIM + lane * 2;
    float2 ca = *reinterpret_cast<const float2*>(cur_aux + base);
    float2 bv = *reinterpret_cast<const float2*>(b + base);
    float ax = bv.x + t * ca.x; float ay = bv.y + t * ca.y;
    float ss = ax * ax + ay * ay;
#pragma unroll
    for (int off = 32; off > 0; off >>= 1) ss += __shfl_xor(ss, off, 64);
    float inv = 1.0f / fmaxf(sqrtf(ss), EPSN);
    float2 o; o.x = ax * inv + ca.x; o.y = ay * inv + ca.y;
    *reinterpret_cast<float2*>(out + base) = o;
}

__global__ void combine_all_kernel(const float* __restrict__ emb, const float* __restrict__ tball,
                                   float* __restrict__ b)
{
    int i = blockIdx.x * blockDim.x + threadIdx.x;
    const int n4 = NNODES * DIM / 4;
    if (i >= n4) return;
    int row = i >> 5;
    float t = tball[row] * (1.0f / 3.0f);
    float4 e  = reinterpret_cast<const float4*>(emb)[i];
    float4 bv = reinterpret_cast<float4*>(b)[i];
    bv.x = t * (e.x + bv.x); bv.y = t * (e.y + bv.y);
    bv.z = t * (e.z + bv.z); bv.w = t * (e.w + bv.w);
    reinterpret_cast<float4*>(b)[i] = bv;
}

__global__ void add_scaled_kernel(const float* __restrict__ a, const float* __restrict__ tbaux,
                                  float* __restrict__ b)
{
    int i = blockIdx.x * blockDim.x + threadIdx.x;
    const int n4 = NNODES * DIM / 4;
    if (i >= n4) return;
    int row = i >> 5;
    float t = tbaux[row] * (1.0f / 3.0f);
    float4 av = reinterpret_cast<const float4*>(a)[i];
    float4 bv = reinterpret_cast<float4*>(b)[i];
    bv.x += t * av.x; bv.y += t * av.y; bv.z += t * av.z; bv.w += t * av.w;
    reinterpret_cast<float4*>(b)[i] = bv;
}

// ===========================================================================
extern "C" void kernel_launch(void* const* d_in, const int* in_sizes, int n_in,
                              void* d_out, int out_size, void* d_ws, size_t ws_size,
                              hipStream_t stream)
{
    const float* emb       = (const float*)d_in[0];
    const int*   rows_aux  = (const int*)d_in[1];
    const int*   cols_aux  = (const int*)d_in[2];
    const float* vals_aux  = (const float*)d_in[3];
    const int*   rows_buy  = (const int*)d_in[4];
    const int*   cols_buy  = (const int*)d_in[5];
    const float* vals_buy  = (const float*)d_in[6];
    const float* t_aux_all = (const float*)d_in[7];
    const float* t_buy_all = (const float*)d_in[8];
    const float* t_buy_aux = (const float*)d_in[9];
    const int*   masks     = (const int*)d_in[10];   // numpy bool widened to int32

    float* out = (float*)d_out;
    const size_t nd = (size_t)NNODES * DIM;
    const size_t nd_bytes = nd * sizeof(float);

    // ---- workspace layout (16B-aligned regions) ----
    uint8_t* wsb = (uint8_t*)d_ws;
    size_t off = 0;
    auto carve = [&](size_t bytes) -> void* {
        void* p = wsb + off;
        off = (off + bytes + 15) & ~(size_t)15;
        return p;
    };
    const int SCAN_BLOCKS = (NN2 + 1023) / 1024;   // 294
    float* B0       = (float*)carve(nd_bytes);
    float* B1       = (float*)carve(nd_bytes);
    uint2* ent      = (uint2*)carve((size_t)2 * NEDGE * 8);
    int*   rp       = (int*)carve(((size_t)NN2 + 1) * 4);
    int*   cursor   = (int*)carve((size_t)NN2 * 4);
    int*   cnt      = (int*)carve((size_t)NN2 * 4);
    int*   partials = (int*)carve((size_t)SCAN_BLOCKS * 4);
    const bool use_csr = (off <= ws_size);

    if (use_csr) {
        const int EB   = 256;
        const int EG2  = (2 * NEDGE + EB - 1) / EB;
        const int GB   = 256;                       // 16 rows/block (16 lanes/row)
        const int GG   = (NNODES * 16 + GB - 1) / GB;

        // ---- CSR build (both adjacencies in one pass) ----
        hipMemsetAsync(cnt, 0, (size_t)NN2 * 4, stream);
        hist_both<<<EG2, EB, 0, stream>>>(rows_aux, rows_buy, cnt);
        scan_phase1<<<SCAN_BLOCKS, 1024, 0, stream>>>(cnt, rp, partials);
        scan_phase2<<<1, 512, 0, stream>>>(partials, SCAN_BLOCKS);
        scan_phase3<<<SCAN_BLOCKS, 1024, 0, stream>>>(rp, partials, cursor);
        scatter_both<<<EG2, EB, 0, stream>>>(rows_aux, cols_aux, vals_aux,
                                             rows_buy, cols_buy, vals_buy,
                                             masks, cursor, ent);

        // ---- Phase A: aux behavior ----
        aux1_kernel<<<GG, GB, 0, stream>>>(rp, ent, emb, B0);
        aux2_kernel<<<GG, GB, 0, stream>>>(rp, ent, B0, emb, t_aux_all, out);

        // ---- Phase B: buy behavior (fused) ----
        buy1_kernel<<<GG, GB, 0, stream>>>(rp + NNODES, ent, emb, out, B0, B1);
        buy2_kernel<<<GG, GB, 0, stream>>>(rp + NNODES, ent, B0, B1, emb,
                                           t_buy_all, t_buy_aux, out);
        return;
    }

    // ---- fallback: Round-3 atomic path ----
    const int SPMM_BLK  = 256;
    const int SPMM_GRID = (int)(((long long)NEDGE * 32 + SPMM_BLK - 1) / SPMM_BLK);
    const int ROW_BLK   = 256;
    const int ROW_GRID  = (NNODES * 64 + ROW_BLK - 1) / ROW_BLK;
    const int EW_BLK    = 256;
    const int EW_GRID   = (int)((nd / 4 + EW_BLK - 1) / EW_BLK);

    hipMemsetAsync(B0, 0, nd_bytes, stream);
    spmm_kernel<<<SPMM_GRID, SPMM_BLK, 0, stream>>>(rows_aux, cols_aux, vals_aux,
                                                    masks + 0 * (size_t)NEDGE, emb, B0);
    hipMemcpyAsync(B1, B0, nd_bytes, hipMemcpyDeviceToDevice, stream);
    spmm_kernel<<<SPMM_GRID, SPMM_BLK, 0, stream>>>(rows_aux, cols_aux, vals_aux,
                                                    masks + 1 * (size_t)NEDGE, B0, B1);
    rownorm_aux_kernel<<<ROW_GRID, ROW_BLK, 0, stream>>>(emb, B1, t_aux_all, out);

    hipMemsetAsync(B0, 0, nd_bytes, stream);
    spmm_kernel<<<SPMM_GRID, SPMM_BLK, 0, stream>>>(rows_buy, cols_buy, vals_buy,
                                                    masks + 2 * (size_t)NEDGE, emb, B0);
    hipMemcpyAsync(B1, B0, nd_bytes, hipMemcpyDeviceToDevice, stream);
    spmm_kernel<<<SPMM_GRID, SPMM_BLK, 0, stream>>>(rows_buy, cols_buy, vals_buy,
                                                    masks + 3 * (size_t)NEDGE, B0, B1);
    combine_all_kernel<<<EW_GRID, EW_BLK, 0, stream>>>(emb, t_buy_all, B1);

    hipMemsetAsync(B0, 0, nd_bytes, stream);
    spmm_kernel<<<SPMM_GRID, SPMM_BLK, 0, stream>>>(rows_buy, cols_buy, vals_buy,
                                                    masks + 4 * (size_t)NEDGE, out, B0);
    add_scaled_kernel<<<EW_GRID, EW_BLK, 0, stream>>>(B0, t_buy_aux, B1);
    spmm_scaled_kernel<<<SPMM_GRID, SPMM_BLK, 0, stream>>>(rows_buy, cols_buy, vals_buy,
                                                           masks + 5 * (size_t)NEDGE, B0, B1,
                                                           t_buy_aux);
    rownorm_final_kernel<<<ROW_GRID, ROW_BLK, 0, stream>>>(out, B1, t_buy_aux, out);
}

// Round 9
// 443.752 us; speedup vs baseline: 7.6620x; 1.1968x over previous
//
#include <hip/hip_runtime.h>
#include <cstdint>
#include <cstddef>

// Problem constants (match reference)
#define NNODES 150002      // N_USERS + N_ITEMS + 2
#define NN2    (2 * NNODES)
#define DIM    128
#define NEDGE  600000
#define EPSN   1e-12f

// ===========================================================================
// CSR-GATHER PATH with bf16 intermediates.
// Concatenated CSR: aux rows [0,N), buy rows [N,2N); ent [0,2E).
// Entry: 8 B = { col | mask_bits<<24 , val }.
// bf16 row = 128 x 2B = 256 B = 16 x uint4; 16 lanes/row, one uint4/lane.
// Buffers: Ebf (bf16 emb), B0bf/B1bf (layer-1 sums), Cbf (bf16 cur_aux).
// fp32 kept for: final output, cur stream in buy2 epilogue.
// ===========================================================================

__device__ __forceinline__ float2 unpack_bf2(unsigned w)
{
    return make_float2(__uint_as_float(w << 16), __uint_as_float(w & 0xFFFF0000u));
}

__device__ __forceinline__ unsigned pack_bf2(float lo, float hi)
{
    unsigned ulo = __float_as_uint(lo); ulo += 0x7FFFu + ((ulo >> 16) & 1u);
    unsigned uhi = __float_as_uint(hi); uhi += 0x7FFFu + ((uhi >> 16) & 1u);
    return (ulo >> 16) | (uhi & 0xFFFF0000u);
}

__device__ __forceinline__ void fma8(float acc[8], float v, uint4 w)
{
    float2 p;
    p = unpack_bf2(w.x); acc[0] = fmaf(v, p.x, acc[0]); acc[1] = fmaf(v, p.y, acc[1]);
    p = unpack_bf2(w.y); acc[2] = fmaf(v, p.x, acc[2]); acc[3] = fmaf(v, p.y, acc[3]);
    p = unpack_bf2(w.z); acc[4] = fmaf(v, p.x, acc[4]); acc[5] = fmaf(v, p.y, acc[5]);
    p = unpack_bf2(w.w); acc[6] = fmaf(v, p.x, acc[6]); acc[7] = fmaf(v, p.y, acc[7]);
}

__device__ __forceinline__ void unpack8(float o[8], uint4 w)
{
    float2 p;
    p = unpack_bf2(w.x); o[0] = p.x; o[1] = p.y;
    p = unpack_bf2(w.y); o[2] = p.x; o[3] = p.y;
    p = unpack_bf2(w.z); o[4] = p.x; o[5] = p.y;
    p = unpack_bf2(w.w); o[6] = p.x; o[7] = p.y;
}

__device__ __forceinline__ uint4 pack8(const float o[8])
{
    uint4 w;
    w.x = pack_bf2(o[0], o[1]); w.y = pack_bf2(o[2], o[3]);
    w.z = pack_bf2(o[4], o[5]); w.w = pack_bf2(o[6], o[7]);
    return w;
}

// ---------------------------------------------------------------------------
// CSR build
// ---------------------------------------------------------------------------
__global__ void hist_both(const int* __restrict__ ra,
                          const int* __restrict__ rb,
                          int* __restrict__ cnt)
{
    int e = blockIdx.x * blockDim.x + threadIdx.x;
    if (e < NEDGE)           atomicAdd(&cnt[ra[e]], 1);
    else if (e < 2 * NEDGE)  atomicAdd(&cnt[NNODES + rb[e - NEDGE]], 1);
}

__global__ __launch_bounds__(1024)
void scan_phase1(const int* __restrict__ cnt,
                 int* __restrict__ local,
                 int* __restrict__ partials)
{
    __shared__ int lds[1024];
    int t = threadIdx.x;
    int i = blockIdx.x * 1024 + t;
    int v = (i < NN2) ? cnt[i] : 0;
    lds[t] = v;
    __syncthreads();
    for (int off = 1; off < 1024; off <<= 1) {
        int w = (t >= off) ? lds[t - off] : 0;
        __syncthreads();
        lds[t] += w;
        __syncthreads();
    }
    if (i < NN2) local[i] = lds[t] - v;
    if (t == 1023) partials[blockIdx.x] = lds[1023];
}

__global__ __launch_bounds__(512)
void scan_phase2(int* __restrict__ partials, int nparts)
{
    __shared__ int lds[512];
    int t = threadIdx.x;
    int v = (t < nparts) ? partials[t] : 0;
    lds[t] = v;
    __syncthreads();
    for (int off = 1; off < 512; off <<= 1) {
        int w = (t >= off) ? lds[t - off] : 0;
        __syncthreads();
        lds[t] += w;
        __syncthreads();
    }
    if (t < nparts) partials[t] = lds[t] - v;
}

__global__ __launch_bounds__(1024)
void scan_phase3(int* __restrict__ rp,
                 const int* __restrict__ partials,
                 int* __restrict__ cursor)
{
    int i = blockIdx.x * 1024 + threadIdx.x;
    if (i >= NN2) return;
    int v = rp[i] + partials[blockIdx.x];
    rp[i] = v;
    cursor[i] = v;
    if (i == 0) rp[NN2] = 2 * NEDGE;
}

__global__ void scatter_both(const int* __restrict__ ra, const int* __restrict__ ca,
                             const float* __restrict__ va,
                             const int* __restrict__ rb, const int* __restrict__ cb,
                             const float* __restrict__ vb,
                             const int* __restrict__ masks,
                             int* __restrict__ cursor,
                             uint2* __restrict__ ent)
{
    int e = blockIdx.x * blockDim.x + threadIdx.x;
    if (e < NEDGE) {
        unsigned bits = (masks[e] != 0 ? 1u : 0u)
                      | (masks[(size_t)NEDGE + e] != 0 ? 2u : 0u);
        int pos = atomicAdd(&cursor[ra[e]], 1);
        ent[pos] = make_uint2((unsigned)ca[e] | (bits << 24), __float_as_uint(va[e]));
    } else if (e < 2 * NEDGE) {
        int e2 = e - NEDGE;
        unsigned bits = 0;
#pragma unroll
        for (int k = 0; k < 4; ++k)
            bits |= (masks[(size_t)(2 + k) * NEDGE + e2] != 0 ? 1u : 0u) << k;
        int pos = atomicAdd(&cursor[NNODES + rb[e2]], 1);
        ent[pos] = make_uint2((unsigned)cb[e2] | (bits << 24), __float_as_uint(vb[e2]));
    }
}

// ---------------------------------------------------------------------------
// fp32 -> bf16 row conversion: one uint4 (8 bf16) per thread.
// ---------------------------------------------------------------------------
__global__ void conv_bf16(const float* __restrict__ x, uint4* __restrict__ xbf)
{
    int i = blockIdx.x * blockDim.x + threadIdx.x;
    const int n = NNODES * 16;
    if (i >= n) return;
    const float4* p = reinterpret_cast<const float4*>(x) + (size_t)i * 2;
    float4 lo = p[0], hi = p[1];
    uint4 w;
    w.x = pack_bf2(lo.x, lo.y); w.y = pack_bf2(lo.z, lo.w);
    w.z = pack_bf2(hi.x, hi.y); w.w = pack_bf2(hi.z, hi.w);
    xbf[i] = w;
}

// ---------------------------------------------------------------------------
// Gather primitives: 16 lanes/row, one uint4 (8 bf16) per lane per edge.
// ---------------------------------------------------------------------------
#define G16_SETUP                                              \
    int gid  = blockIdx.x * blockDim.x + threadIdx.x;          \
    int row  = gid >> 4;                                       \
    int lane = gid & 15;                                       \
    if (row >= NNODES) return;

__device__ __forceinline__ void gatherbf_1(const int* __restrict__ rp,
                                           const uint2* __restrict__ ent,
                                           unsigned bm, int row, int lane,
                                           const uint4* __restrict__ xbf,
                                           float acc[8])
{
    int j0 = rp[row], j1 = rp[row + 1];
    float a0[8] = {0,0,0,0,0,0,0,0}, a1[8] = {0,0,0,0,0,0,0,0};
    int j = j0;
    for (; j + 2 <= j1; j += 2) {
        uint2 Ea = ent[j], Eb = ent[j + 1];
        bool ma = (Ea.x & bm) != 0, mb = (Eb.x & bm) != 0;
        uint4 wa, wb;
        if (ma) wa = xbf[(size_t)(Ea.x & 0xFFFFFFu) * 16 + lane];
        if (mb) wb = xbf[(size_t)(Eb.x & 0xFFFFFFu) * 16 + lane];
        if (ma) fma8(a0, __uint_as_float(Ea.y), wa);
        if (mb) fma8(a1, __uint_as_float(Eb.y), wb);
    }
    if (j < j1) {
        uint2 E = ent[j];
        if ((E.x & bm) != 0) {
            uint4 w = xbf[(size_t)(E.x & 0xFFFFFFu) * 16 + lane];
            fma8(a0, __uint_as_float(E.y), w);
        }
    }
#pragma unroll
    for (int k = 0; k < 8; ++k) acc[k] = a0[k] + a1[k];
}

__device__ __forceinline__ void gatherbf_2(const int* __restrict__ rp,
                                           const uint2* __restrict__ ent,
                                           int row, int lane,
                                           const uint4* __restrict__ xA, unsigned bmA,
                                           const uint4* __restrict__ xB, unsigned bmB,
                                           float accA[8], float accB[8])
{
    int j0 = rp[row], j1 = rp[row + 1];
#pragma unroll
    for (int k = 0; k < 8; ++k) { accA[k] = 0.f; accB[k] = 0.f; }
    int j = j0;
    for (; j + 2 <= j1; j += 2) {
        uint2 Ea = ent[j], Eb = ent[j + 1];
        size_t ia = (size_t)(Ea.x & 0xFFFFFFu) * 16 + lane;
        size_t ib = (size_t)(Eb.x & 0xFFFFFFu) * 16 + lane;
        bool maA = (Ea.x & bmA) != 0, maB = (Ea.x & bmB) != 0;
        bool mbA = (Eb.x & bmA) != 0, mbB = (Eb.x & bmB) != 0;
        uint4 waA, waB, wbA, wbB;
        if (maA) waA = xA[ia];
        if (maB) waB = xB[ia];
        if (mbA) wbA = xA[ib];
        if (mbB) wbB = xB[ib];
        float va = __uint_as_float(Ea.y), vb = __uint_as_float(Eb.y);
        if (maA) fma8(accA, va, waA);
        if (maB) fma8(accB, va, waB);
        if (mbA) fma8(accA, vb, wbA);
        if (mbB) fma8(accB, vb, wbB);
    }
    if (j < j1) {
        uint2 E = ent[j];
        size_t ic = (size_t)(E.x & 0xFFFFFFu) * 16 + lane;
        bool mA = (E.x & bmA) != 0, mB = (E.x & bmB) != 0;
        uint4 wA, wB;
        if (mA) wA = xA[ic];
        if (mB) wB = xB[ic];
        float v = __uint_as_float(E.y);
        if (mA) fma8(accA, v, wA);
        if (mB) fma8(accB, v, wB);
    }
}

// aux layer 1: B0bf[row] = bf16( sum_{bit0} v * Ebf[col] )
__global__ void aux1_kernel(const int* __restrict__ rp, const uint2* __restrict__ ent,
                            const uint4* __restrict__ Ebf, uint4* __restrict__ B0bf)
{
    G16_SETUP
    float acc[8];
    gatherbf_1(rp, ent, 1u << 24, row, lane, Ebf, acc);
    B0bf[(size_t)row * 16 + lane] = pack8(acc);
}

// aux layer 2 + epilogue:
// a = t/3*(emb + B0 + gather_bit1(B0)); cur = l2norm(a) + emb
// writes: out (fp32), Cbf (bf16 cur)
__global__ void aux2_kernel(const int* __restrict__ rp, const uint2* __restrict__ ent,
                            const uint4* __restrict__ B0bf, const uint4* __restrict__ Ebf,
                            const float* __restrict__ trans,
                            float* __restrict__ out, uint4* __restrict__ Cbf)
{
    G16_SETUP
    float acc[8];
    gatherbf_1(rp, ent, 1u << 25, row, lane, B0bf, acc);
    size_t ri = (size_t)row * 16 + lane;
    float e8[8], b8[8];
    unpack8(e8, Ebf[ri]);
    unpack8(b8, B0bf[ri]);
    float t = trans[row] * (1.0f / 3.0f);
    float a[8], ss = 0.f;
#pragma unroll
    for (int k = 0; k < 8; ++k) { a[k] = t * (e8[k] + b8[k] + acc[k]); ss += a[k] * a[k]; }
#pragma unroll
    for (int off = 8; off > 0; off >>= 1) ss += __shfl_xor(ss, off, 64);
    float inv = 1.0f / fmaxf(sqrtf(ss), EPSN);
    float o[8];
#pragma unroll
    for (int k = 0; k < 8; ++k) o[k] = a[k] * inv + e8[k];
    float* op = out + (size_t)row * DIM + lane * 8;
    *reinterpret_cast<float4*>(op)     = make_float4(o[0], o[1], o[2], o[3]);
    *reinterpret_cast<float4*>(op + 4) = make_float4(o[4], o[5], o[6], o[7]);
    Cbf[ri] = pack8(o);
}

// buy layer 1: B0bf[row]=bf16(sum_{bit0} v*Ebf[col]); B1bf[row]=bf16(sum_{bit2} v*Cbf[col])
__global__ void buy1_kernel(const int* __restrict__ rp, const uint2* __restrict__ ent,
                            const uint4* __restrict__ Ebf, const uint4* __restrict__ Cbf,
                            uint4* __restrict__ B0bf, uint4* __restrict__ B1bf)
{
    G16_SETUP
    float accA[8], accX[8];
    gatherbf_2(rp, ent, row, lane, Ebf, 1u << 24, Cbf, 1u << 26, accA, accX);
    size_t ri = (size_t)row * 16 + lane;
    B0bf[ri] = pack8(accA);
    B1bf[ri] = pack8(accX);
}

// buy layer 2 + full epilogue:
// agg = tall/3*(emb+B0+gather_bit1(B0)) + taux/3*(cur+B1+gather_bit3(B1))
// out = l2norm(agg) + cur      (cur streamed fp32 from out; in-place, row-local)
__global__ void buy2_kernel(const int* __restrict__ rp, const uint2* __restrict__ ent,
                            const uint4* __restrict__ B0bf, const uint4* __restrict__ B1bf,
                            const uint4* __restrict__ Ebf,
                            const float* __restrict__ tall, const float* __restrict__ taux,
                            float* __restrict__ out)
{
    G16_SETUP
    float accA[8], accX[8];
    gatherbf_2(rp, ent, row, lane, B0bf, 1u << 25, B1bf, 1u << 27, accA, accX);
    size_t ri = (size_t)row * 16 + lane;
    float e8[8], b0[8], b1[8];
    unpack8(e8, Ebf[ri]);
    unpack8(b0, B0bf[ri]);
    unpack8(b1, B1bf[ri]);
    float* op = out + (size_t)row * DIM + lane * 8;
    float4 c0 = *reinterpret_cast<const float4*>(op);
    float4 c1 = *reinterpret_cast<const float4*>(op + 4);
    float c8[8] = {c0.x, c0.y, c0.z, c0.w, c1.x, c1.y, c1.z, c1.w};
    float ta = tall[row] * (1.0f / 3.0f);
    float tx = taux[row] * (1.0f / 3.0f);
    float a[8], ss = 0.f;
#pragma unroll
    for (int k = 0; k < 8; ++k) {
        a[k] = ta * (e8[k] + b0[k] + accA[k]) + tx * (c8[k] + b1[k] + accX[k]);
        ss += a[k] * a[k];
    }
#pragma unroll
    for (int off = 8; off > 0; off >>= 1) ss += __shfl_xor(ss, off, 64);
    float inv = 1.0f / fmaxf(sqrtf(ss), EPSN);
    float o[8];
#pragma unroll
    for (int k = 0; k < 8; ++k) o[k] = a[k] * inv + c8[k];
    *reinterpret_cast<float4*>(op)     = make_float4(o[0], o[1], o[2], o[3]);
    *reinterpret_cast<float4*>(op + 4) = make_float4(o[4], o[5], o[6], o[7]);
}

// ===========================================================================
// FALLBACK PATH (Round-3 proven atomic scatter) — used only if ws too small.
// ===========================================================================
__global__ void spmm_kernel(const int* __restrict__ rows, const int* __restrict__ cols,
                            const float* __restrict__ vals, const int* __restrict__ mask,
                            const float* __restrict__ x, float* __restrict__ y)
{
    long long gid = (long long)blockIdx.x * blockDim.x + threadIdx.x;
    int e = (int)(gid >> 5); int lane = (int)(gid & 31);
    if (e >= NEDGE) return;
    if (!mask[e]) return;
    float v = vals[e]; int c = cols[e]; int r = rows[e];
    float4 xv = *reinterpret_cast<const float4*>(x + (size_t)c * DIM + lane * 4);
    float* dst = y + (size_t)r * DIM + lane * 4;
    atomicAdd(dst + 0, v * xv.x); atomicAdd(dst + 1, v * xv.y);
    atomicAdd(dst + 2, v * xv.z); atomicAdd(dst + 3, v * xv.w);
}

__global__ void spmm_scaled_kernel(const int* __restrict__ rows, const int* __restrict__ cols,
                                   const float* __restrict__ vals, const int* __restrict__ mask,
                                   const float* __restrict__ x, float* __restrict__ y,
                                   const float* __restrict__ rowscale)
{
    long long gid = (long long)blockIdx.x * blockDim.x + threadIdx.x;
    int e = (int)(gid >> 5); int lane = (int)(gid & 31);
    if (e >= NEDGE) return;
    if (!mask[e]) return;
    int r = rows[e];
    float v = vals[e] * rowscale[r] * (1.0f / 3.0f);
    int c = cols[e];
    float4 xv = *reinterpret_cast<const float4*>(x + (size_t)c * DIM + lane * 4);
    float* dst = y + (size_t)r * DIM + lane * 4;
    atomicAdd(dst + 0, v * xv.x); atomicAdd(dst + 1, v * xv.y);
    atomicAdd(dst + 2, v * xv.z); atomicAdd(dst + 3, v * xv.w);
}

__global__ void rownorm_aux_kernel(const float* __restrict__ emb, const float* __restrict__ s,
                                   const float* __restrict__ trans, float* __restrict__ out)
{
    int gid = blockIdx.x * blockDim.x + threadIdx.x;
    int row = gid >> 6; int lane = gid & 63;
    if (row >= NNODES) return;
    float t = trans[row] * (1.0f / 3.0f);
    size_t base = (size_t)row * DIM + lane * 2;
    float2 e  = *reinterpret_cast<const float2*>(emb + base);
    float2 sv = *reinterpret_cast<const float2*>(s + base);
    float ax = t * (e.x + sv.x); float ay = t * (e.y + sv.y);
    float ss = ax * ax + ay * ay;
#pragma unroll
    for (int off = 32; off > 0; off >>= 1) ss += __shfl_xor(ss, off, 64);
    float inv = 1.0f / fmaxf(sqrtf(ss), EPSN);
    float2 o; o.x = ax * inv + e.x; o.y = ay * inv + e.y;
    *reinterpret_cast<float2*>(out + base) = o;
}

__global__ void rownorm_final_kernel(const float* __restrict__ cur_aux, const float* __restrict__ b,
                                     const float* __restrict__ tbaux, float* __restrict__ out)
{
    int gid = blockIdx.x * blockDim.x + threadIdx.x;
    int row = gid >> 6; int lane = gid & 63;
    if (row >= NNODES) return;
    float t = tbaux[row] * (1.0f / 3.0f);
    size_t base = (size_t)row * DIM + lane * 2;
    float2 ca = *reinterpret_cast<const float2*>(cur_aux + base);
    float2 bv = *reinterpret_cast<const float2*>(b + base);
    float ax = bv.x + t * ca.x; float ay = bv.y + t * ca.y;
    float ss = ax * ax + ay * ay;
#pragma unroll
    for (int off = 32; off > 0; off >>= 1) ss += __shfl_xor(ss, off, 64);
    float inv = 1.0f / fmaxf(sqrtf(ss), EPSN);
    float2 o; o.x = ax * inv + ca.x; o.y = ay * inv + ca.y;
    *reinterpret_cast<float2*>(out + base) = o;
}

__global__ void combine_all_kernel(const float* __restrict__ emb, const float* __restrict__ tball,
                                   float* __restrict__ b)
{
    int i = blockIdx.x * blockDim.x + threadIdx.x;
    const int n4 = NNODES * DIM / 4;
    if (i >= n4) return;
    int row = i >> 5;
    float t = tball[row] * (1.0f / 3.0f);
    float4 e  = reinterpret_cast<const float4*>(emb)[i];
    float4 bv = reinterpret_cast<float4*>(b)[i];
    bv.x = t * (e.x + bv.x); bv.y = t * (e.y + bv.y);
    bv.z = t * (e.z + bv.z); bv.w = t * (e.w + bv.w);
    reinterpret_cast<float4*>(b)[i] = bv;
}

__global__ void add_scaled_kernel(const float* __restrict__ a, const float* __restrict__ tbaux,
                                  float* __restrict__ b)
{
    int i = blockIdx.x * blockDim.x + threadIdx.x;
    const int n4 = NNODES * DIM / 4;
    if (i >= n4) return;
    int row = i >> 5;
    float t = tbaux[row] * (1.0f / 3.0f);
    float4 av = reinterpret_cast<const float4*>(a)[i];
    float4 bv = reinterpret_cast<float4*>(b)[i];
    bv.x += t * av.x; bv.y += t * av.y; bv.z += t * av.z; bv.w += t * av.w;
    reinterpret_cast<float4*>(b)[i] = bv;
}

// ===========================================================================
extern "C" void kernel_launch(void* const* d_in, const int* in_sizes, int n_in,
                              void* d_out, int out_size, void* d_ws, size_t ws_size,
                              hipStream_t stream)
{
    const float* emb       = (const float*)d_in[0];
    const int*   rows_aux  = (const int*)d_in[1];
    const int*   cols_aux  = (const int*)d_in[2];
    const float* vals_aux  = (const float*)d_in[3];
    const int*   rows_buy  = (const int*)d_in[4];
    const int*   cols_buy  = (const int*)d_in[5];
    const float* vals_buy  = (const float*)d_in[6];
    const float* t_aux_all = (const float*)d_in[7];
    const float* t_buy_all = (const float*)d_in[8];
    const float* t_buy_aux = (const float*)d_in[9];
    const int*   masks     = (const int*)d_in[10];   // numpy bool widened to int32

    float* out = (float*)d_out;
    const size_t nd = (size_t)NNODES * DIM;
    const size_t nd_bytes = nd * sizeof(float);
    const size_t bf_bytes = nd * 2;                  // bf16 buffer bytes

    // ---- workspace layout (16B-aligned regions) ----
    uint8_t* wsb = (uint8_t*)d_ws;
    size_t off = 0;
    auto carve = [&](size_t bytes) -> void* {
        void* p = wsb + off;
        off = (off + bytes + 15) & ~(size_t)15;
        return p;
    };
    const int SCAN_BLOCKS = (NN2 + 1023) / 1024;   // 294
    uint4* Ebf      = (uint4*)carve(bf_bytes);
    uint4* B0bf     = (uint4*)carve(bf_bytes);
    uint4* B1bf     = (uint4*)carve(bf_bytes);
    uint4* Cbf      = (uint4*)carve(bf_bytes);
    uint2* ent      = (uint2*)carve((size_t)2 * NEDGE * 8);
    int*   rp       = (int*)carve(((size_t)NN2 + 1) * 4);
    int*   cursor   = (int*)carve((size_t)NN2 * 4);
    int*   cnt      = (int*)carve((size_t)NN2 * 4);
    int*   partials = (int*)carve((size_t)SCAN_BLOCKS * 4);
    const bool use_csr = (off <= ws_size);

    if (use_csr) {
        const int EB   = 256;
        const int EG2  = (2 * NEDGE + EB - 1) / EB;
        const int GB   = 256;                       // 16 rows/block (16 lanes/row)
        const int GG   = (NNODES * 16 + GB - 1) / GB;

        // ---- emb -> bf16 (independent of CSR build) ----
        conv_bf16<<<GG, GB, 0, stream>>>(emb, Ebf);

        // ---- CSR build (both adjacencies in one pass) ----
        hipMemsetAsync(cnt, 0, (size_t)NN2 * 4, stream);
        hist_both<<<EG2, EB, 0, stream>>>(rows_aux, rows_buy, cnt);
        scan_phase1<<<SCAN_BLOCKS, 1024, 0, stream>>>(cnt, rp, partials);
        scan_phase2<<<1, 512, 0, stream>>>(partials, SCAN_BLOCKS);
        scan_phase3<<<SCAN_BLOCKS, 1024, 0, stream>>>(rp, partials, cursor);
        scatter_both<<<EG2, EB, 0, stream>>>(rows_aux, cols_aux, vals_aux,
                                             rows_buy, cols_buy, vals_buy,
                                             masks, cursor, ent);

        // ---- Phase A: aux behavior ----
        aux1_kernel<<<GG, GB, 0, stream>>>(rp, ent, Ebf, B0bf);
        aux2_kernel<<<GG, GB, 0, stream>>>(rp, ent, B0bf, Ebf, t_aux_all, out, Cbf);

        // ---- Phase B: buy behavior (fused) ----
        buy1_kernel<<<GG, GB, 0, stream>>>(rp + NNODES, ent, Ebf, Cbf, B0bf, B1bf);
        buy2_kernel<<<GG, GB, 0, stream>>>(rp + NNODES, ent, B0bf, B1bf, Ebf,
                                           t_buy_all, t_buy_aux, out);
        return;
    }

    // ---- fallback: Round-3 atomic path (fp32, reuses ws from the start) ----
    float* B0 = (float*)d_ws;
    float* B1 = B0 + nd;

    const int SPMM_BLK  = 256;
    const int SPMM_GRID = (int)(((long long)NEDGE * 32 + SPMM_BLK - 1) / SPMM_BLK);
    const int ROW_BLK   = 256;
    const int ROW_GRID  = (NNODES * 64 + ROW_BLK - 1) / ROW_BLK;
    const int EW_BLK    = 256;
    const int EW_GRID   = (int)((nd / 4 + EW_BLK - 1) / EW_BLK);

    hipMemsetAsync(B0, 0, nd_bytes, stream);
    spmm_kernel<<<SPMM_GRID, SPMM_BLK, 0, stream>>>(rows_aux, cols_aux, vals_aux,
                                                    masks + 0 * (size_t)NEDGE, emb, B0);
    hipMemcpyAsync(B1, B0, nd_bytes, hipMemcpyDeviceToDevice, stream);
    spmm_kernel<<<SPMM_GRID, SPMM_BLK, 0, stream>>>(rows_aux, cols_aux, vals_aux,
                                                    masks + 1 * (size_t)NEDGE, B0, B1);
    rownorm_aux_kernel<<<ROW_GRID, ROW_BLK, 0, stream>>>(emb, B1, t_aux_all, out);

    hipMemsetAsync(B0, 0, nd_bytes, stream);
    spmm_kernel<<<SPMM_GRID, SPMM_BLK, 0, stream>>>(rows_buy, cols_buy, vals_buy,
                                                    masks + 2 * (size_t)NEDGE, emb, B0);
    hipMemcpyAsync(B1, B0, nd_bytes, hipMemcpyDeviceToDevice, stream);
    spmm_kernel<<<SPMM_GRID, SPMM_BLK, 0, stream>>>(rows_buy, cols_buy, vals_buy,
                                                    masks + 3 * (size_t)NEDGE, B0, B1);
    combine_all_kernel<<<EW_GRID, EW_BLK, 0, stream>>>(emb, t_buy_all, B1);

    hipMemsetAsync(B0, 0, nd_bytes, stream);
    spmm_kernel<<<SPMM_GRID, SPMM_BLK, 0, stream>>>(rows_buy, cols_buy, vals_buy,
                                                    masks + 4 * (size_t)NEDGE, out, B0);
    add_scaled_kernel<<<EW_GRID, EW_BLK, 0, stream>>>(B0, t_buy_aux, B1);
    spmm_scaled_kernel<<<SPMM_GRID, SPMM_BLK, 0, stream>>>(rows_buy, cols_buy, vals_buy,
                                                           masks + 5 * (size_t)NEDGE, B0, B1,
                                                           t_buy_aux);
    rownorm_final_kernel<<<ROW_GRID, ROW_BLK, 0, stream>>>(out, B1, t_buy_aux, out);
}